// Round 4
// baseline (185.415 us; speedup 1.0000x reference)
//
#include <hip/hip_runtime.h>
#include <stdint.h>

typedef __bf16 bf16_t;
typedef __bf16 bf16x4 __attribute__((ext_vector_type(4)));
typedef __bf16 bf16x8 __attribute__((ext_vector_type(8)));
typedef float  f32x4  __attribute__((ext_vector_type(4)));
typedef float  f32x16 __attribute__((ext_vector_type(16)));

#define D_MODEL 1024
#define SEQ     2048
#define BATCH   2
#define NHEAD   16
#define DHEAD   64
#define NROWS   (BATCH*SEQ)   // 4096
#define LDT     72            // GEMM V-transpose buffer stride (16B-aligned)

// log2(e): folded into Q scale so attn uses v_exp_f32 (exp2) directly.
#define QSCALE  (0.125f * 1.4426950408889634f)

// async 16B global->LDS DMA (m97). LDS dest must be wave-uniform base + lane*16.
__device__ __forceinline__ void async_ld16(const bf16_t* g, bf16_t* l) {
    __builtin_amdgcn_global_load_lds(
        (const __attribute__((address_space(1))) uint32_t*)(uintptr_t)g,
        (__attribute__((address_space(3))) uint32_t*)(uintptr_t)l,
        16, 0, 0);
}

__device__ __forceinline__ bf16x8 cvt8(f32x4 lo, f32x4 hi) {
    bf16x8 o;
#pragma unroll
    for (int i = 0; i < 4; ++i) { o[i] = (bf16_t)lo[i]; o[4 + i] = (bf16_t)hi[i]; }
    return o;
}

// v_permlane32_swap_b32 a, b:  a' = {a[0:31], b[0:31]},  b' = {a[32:63], b[32:63]}
__device__ __forceinline__ void plswap(uint32_t& a, uint32_t& b) {
    asm("v_permlane32_swap_b32 %0, %1" : "+v"(a), "+v"(b));
}

// ---------------------------------------------------------------------------
// f32 -> bf16 pre-convert of Wq,Wk,Wv,Wo (512 blocks each) + x (2048 blocks).
// ---------------------------------------------------------------------------
__global__ void __launch_bounds__(256)
k_cvt(const float* __restrict__ w0, const float* __restrict__ w1,
      const float* __restrict__ w2, const float* __restrict__ w3,
      const float* __restrict__ x,
      bf16_t* __restrict__ o0, bf16_t* __restrict__ o1,
      bf16_t* __restrict__ o2, bf16_t* __restrict__ o3,
      bf16_t* __restrict__ ox)
{
    const int blk = blockIdx.x;
    const float* s; bf16_t* d; int bi;
    if (blk < 2048) { s = x; d = ox; bi = blk; }
    else {
        const int t = blk - 2048, sel = t >> 9; bi = t & 511;
        s = (sel == 0) ? w0 : (sel == 1) ? w1 : (sel == 2) ? w2 : w3;
        d = (sel == 0) ? o0 : (sel == 1) ? o1 : (sel == 2) ? o2 : o3;
    }
    const size_t i = ((size_t)bi * 256 + threadIdx.x) * 8;
    *(bf16x8*)(d + i) = cvt8(*(const f32x4*)(s + i), *(const f32x4*)(s + i + 4));
}

// ---------------------------------------------------------------------------
// 128x128 GEMM tile: Y = X @ W^T * oscale. A and B bf16. (round-8 structure)
// Staging: global_load_lds width=16, 32-elem LDS rows, XOR-4 chunk swizzle.
// OUT_MODE: 0 = bf16 row-major; 1 = bf16 V^T [bh][dh][s]; 2 = f32 row-major.
// ---------------------------------------------------------------------------
template <int OUT_MODE>
__device__ __forceinline__ void gemm128(bf16_t* __restrict__ smem,
                                        const bf16_t* __restrict__ X,
                                        const bf16_t* __restrict__ W,
                                        void* __restrict__ Yv,
                                        int m0, int n0, float oscale)
{
    bf16_t* lA = smem;                 // 128 x 32
    bf16_t* lB = smem + 128 * 32;      // 128 x 32

    const int tid  = threadIdx.x;
    const int lane = tid & 63;
    const int w    = tid >> 6;
    const int l15  = lane & 15;
    const int quad = lane >> 4;

    const int c0 = tid, c1 = tid + 256;
    const int r0 = c0 >> 2, r1 = c1 >> 2;
    const int kc0 = (c0 & 3) ^ ((r0 >> 1) & 3);
    const int kc1 = (c1 & 3) ^ ((r1 >> 1) & 3);
    const bf16_t* gA0 = X + (size_t)(m0 + r0) * D_MODEL + kc0 * 8;
    const bf16_t* gA1 = X + (size_t)(m0 + r1) * D_MODEL + kc1 * 8;
    const bf16_t* gB0 = W + (size_t)(n0 + r0) * D_MODEL + kc0 * 8;
    const bf16_t* gB1 = W + (size_t)(n0 + r1) * D_MODEL + kc1 * 8;

    int am[4], bn[4];
    const int mw = (w >> 1) * 64, nw = (w & 1) * 64;
#pragma unroll
    for (int i = 0; i < 4; ++i) {
        const int ra = mw + i * 16 + l15;
        am[i] = ra * 32 + (quad ^ ((ra >> 1) & 3)) * 8;
        const int rb = nw + i * 16 + l15;
        bn[i] = rb * 32 + (quad ^ ((rb >> 1) & 3)) * 8;
    }

    f32x4 acc[4][4];
#pragma unroll
    for (int i = 0; i < 4; ++i)
#pragma unroll
        for (int j = 0; j < 4; ++j) acc[i][j] = f32x4{0.f, 0.f, 0.f, 0.f};

    for (int k0 = 0; k0 < D_MODEL; k0 += 32) {
        __syncthreads();
        async_ld16(gA0 + k0, &lA[c0 * 8]);
        async_ld16(gA1 + k0, &lA[c1 * 8]);
        async_ld16(gB0 + k0, &lB[c0 * 8]);
        async_ld16(gB1 + k0, &lB[c1 * 8]);
        __syncthreads();

        bf16x8 af[4], bfr[4];
#pragma unroll
        for (int i = 0; i < 4; ++i) af[i]  = *(const bf16x8*)&lA[am[i]];
#pragma unroll
        for (int i = 0; i < 4; ++i) bfr[i] = *(const bf16x8*)&lB[bn[i]];
#pragma unroll
        for (int mi = 0; mi < 4; ++mi)
#pragma unroll
            for (int ni = 0; ni < 4; ++ni)
                acc[mi][ni] = __builtin_amdgcn_mfma_f32_16x16x32_bf16(
                    af[mi], bfr[ni], acc[mi][ni], 0, 0, 0);
    }

    if constexpr (OUT_MODE == 1) {
        bf16_t* lT = smem;                        // 128 cols x LDT
#pragma unroll
        for (int h0 = 0; h0 < 2; ++h0) {
            __syncthreads();
            if ((w >> 1) == h0) {
#pragma unroll
                for (int mi = 0; mi < 4; ++mi)
#pragma unroll
                    for (int ni = 0; ni < 4; ++ni) {
                        bf16x4 pk;
#pragma unroll
                        for (int r = 0; r < 4; ++r)
                            pk[r] = (bf16_t)(acc[mi][ni][r] * oscale);
                        const int col = nw + ni * 16 + l15;
                        *(bf16x4*)&lT[col * LDT + mi * 16 + quad * 4] = pk;
                    }
            }
            __syncthreads();
            const int col = tid & 127;
            const int seg = tid >> 7;
            const int brow = m0 + h0 * 64;
            const int b = brow >> 11, sb = brow & 2047;
            const int cg = n0 + col;              // h*64+dh
            bf16_t* dst = (bf16_t*)Yv +
                ((size_t)((b << 4) | (cg >> 6)) * 64 + (cg & 63)) * SEQ + sb;
#pragma unroll
            for (int u = 0; u < 4; ++u)
                *(bf16x8*)(dst + seg * 32 + u * 8) =
                    *(const bf16x8*)&lT[col * LDT + seg * 32 + u * 8];
        }
    } else {
        // C/D layout col = lane&15, row = quad*4 + reg (m89-verified)
#pragma unroll
        for (int mi = 0; mi < 4; ++mi)
#pragma unroll
            for (int ni = 0; ni < 4; ++ni)
#pragma unroll
                for (int r = 0; r < 4; ++r) {
                    const int row = m0 + mw + mi * 16 + quad * 4 + r;
                    const int col = n0 + nw + ni * 16 + l15;
                    const float vv = acc[mi][ni][r] * oscale;
                    if constexpr (OUT_MODE == 0)
                        ((bf16_t*)Yv)[(size_t)row * D_MODEL + col] = (bf16_t)vv;
                    else
                        ((float*)Yv)[(size_t)row * D_MODEL + col] = vv;
                }
    }
}

__global__ void __launch_bounds__(256, 3)
k_gemm_qkv(const bf16_t* __restrict__ X,
           const bf16_t* __restrict__ Wq, const bf16_t* __restrict__ Wk,
           const bf16_t* __restrict__ Wv,
           bf16_t* __restrict__ Qb, bf16_t* __restrict__ Kb, bf16_t* __restrict__ Vt)
{
    __shared__ __align__(16) bf16_t smem[128 * LDT];   // 18432 B
    const int sel = blockIdx.y >> 3;           // 0=Q 1=K 2=V
    const int n0  = (blockIdx.y & 7) * 128;
    const int m0  = blockIdx.x * 128;
    if (sel == 0)      gemm128<0>(smem, X, Wq, Qb, m0, n0, QSCALE);
    else if (sel == 1) gemm128<0>(smem, X, Wk, Kb, m0, n0, 1.0f);
    else               gemm128<1>(smem, X, Wv, Vt, m0, n0, 1.0f);
}

__global__ void __launch_bounds__(256, 3)
k_gemm_out(const bf16_t* __restrict__ X, const bf16_t* __restrict__ W,
           float* __restrict__ Y)
{
    __shared__ __align__(16) bf16_t smem[128 * LDT];
    gemm128<2>(smem, X, W, Y, blockIdx.x * 128, blockIdx.y * 128, 1.0f);
}

// ---------------------------------------------------------------------------
// Attention, Q-tile 64 (round-4: was 128). Grid (32 bh, 32 q-tiles) = 1024
// blocks = 4 blocks/CU = 4 waves/SIMD. Round-3 post-mortem: each wave is ~62%
// dependency-stalled (ds_read -> QK MFMA -> exp2 -> pack -> PV -> barrier is
// one serial chain); 2 waves/SIMD could not cover it and the inter-block
// stagger was null. Same math, half the per-wave work, double the TLP.
// 4 waves per block in a 2x2 split: wq = 32-row q-strip, wk = 32-row kv-half.
// Per wave-iter: 4 K-frag + 4 V-frag ds_read_b128, 4 QK + 6 PV MFMAs, 16
// exp2. Partner h-exchange via v_permlane32_swap_b32 (VALU). Row-sum via
// ones-column MFMA (acc_s layout == acc_o). Double-buffered K/V, stage t+1
// before compute of t, one fused vmcnt/lgkmcnt+barrier per tile. Epilogue
// combines wk pairs through the (reused) LDS arena once.
// Ob may alias Qb (Q read to regs up-front; block-disjoint row/col slices).
// ---------------------------------------------------------------------------
__global__ void __launch_bounds__(256, 4)
k_attn(const bf16_t* __restrict__ Qb, const bf16_t* __restrict__ Kb,
       const bf16_t* __restrict__ Vt, bf16_t* __restrict__ Ob)
{
    // arena: main loop lK[2][4096]+lV[2][4096] bf16 = 32 KiB;
    // epilogue reuses it as 128 blobs of 48 floats (stride 52 -> 26.6 KiB).
    __shared__ __align__(16) char arena[32768];
    bf16_t* lK = (bf16_t*)arena;               // [2][64*64] swizzled chunks
    bf16_t* lV = (bf16_t*)(arena + 16384);     // [2][64*64] swizzled chunks

    const int tid  = threadIdx.x;
    const int lane = tid & 63;
    const int w    = tid >> 6;
    const int wq   = w >> 1;      // q-strip (32 rows)
    const int wk   = w & 1;       // kv-half (32 rows)
    const int l31  = lane & 31;
    const int h    = lane >> 5;

    const int bh = blockIdx.x;    // 0..31
    const int b_ = bh >> 4, hh = bh & 15;
    const int q0 = blockIdx.y * 64;

    const size_t base = (size_t)b_ * SEQ * D_MODEL + (size_t)hh * DHEAD;
    const bf16_t* Qp = Qb + base;
    const bf16_t* Kp = Kb + base;
    const bf16_t* Vp = Vt + (size_t)bh * DHEAD * SEQ;   // [dh][s]

    // Q B-frags in regs: B[n = q = l31][k = dh-local c*16 + h*8 + j]
    const int qrow = q0 + wq * 32 + l31;
    bf16x8 qf[4];
#pragma unroll
    for (int c = 0; c < 4; ++c)
        qf[c] = *(const bf16x8*)&Qp[(size_t)qrow * D_MODEL + c * 16 + h * 8];

    // staging: 512 chunks per tile, 2 per thread; chunk c -> row c>>3, slot
    // c&7, global chunk g = (c&7) ^ (row&7). Note (r0+32)&7 == r0&7.
    const int c0 = tid, c1 = tid + 256;
    const int r0 = c0 >> 3, g0 = (c0 & 7) ^ (r0 & 7);
    const int r1 = r0 + 32;
    const bf16_t* gK0 = Kp + (size_t)r0 * D_MODEL + g0 * 8;
    const bf16_t* gK1 = Kp + (size_t)r1 * D_MODEL + g0 * 8;
    const bf16_t* gV0 = Vp + (size_t)r0 * SEQ + g0 * 8;
    const bf16_t* gV1 = Vp + (size_t)r1 * SEQ + g0 * 8;

    // fragment read offsets (row-dependent XOR slot)
    int koff[4], voff[2][2];
#pragma unroll
    for (int c = 0; c < 4; ++c) {
        const int row = wk * 32 + l31;               // kv row (wave's half)
        koff[c] = row * 64 + (((2 * c + h) ^ (row & 7)) * 8);
    }
#pragma unroll
    for (int a = 0; a < 2; ++a)
#pragma unroll
        for (int ck = 0; ck < 2; ++ck) {
            const int row = a * 32 + l31;            // dh row
            const int ch  = 4 * wk + 2 * ck + h;     // kv chunk within row
            voff[a][ck] = row * 64 + ((ch ^ (row & 7)) * 8);
        }

    bf16x8 onef;
#pragma unroll
    for (int i = 0; i < 8; ++i) onef[i] = (bf16_t)1.0f;

    f32x16 acc_o[2];               // [a]  D[m=q][n=dh half]
    f32x16 acc_s;                  // rowsum (ones-column PV), partial over wk
#pragma unroll
    for (int i = 0; i < 16; ++i) { acc_o[0][i] = 0.f; acc_o[1][i] = 0.f; acc_s[i] = 0.f; }

    // ---- prologue: stage tile 0 into buf 0, drain, barrier
    async_ld16(gK0, &lK[c0 * 8]);
    async_ld16(gK1, &lK[c1 * 8]);
    async_ld16(gV0, &lV[c0 * 8]);
    async_ld16(gV1, &lV[c1 * 8]);
    asm volatile("s_waitcnt vmcnt(0)\n\ts_barrier" ::: "memory");

    int cur = 0;
    const int NT = SEQ / 64;       // 32
    for (int t = 0; t < NT; ++t) {
        // ---- issue next-tile DMA first; latency hides under this tile's math
        if (t + 1 < NT) {
            const int kv0 = (t + 1) * 64;
            const int nb = (cur ^ 1) * 4096;
            async_ld16(gK0 + (size_t)kv0 * D_MODEL, &lK[nb + c0 * 8]);
            async_ld16(gK1 + (size_t)kv0 * D_MODEL, &lK[nb + c1 * 8]);
            async_ld16(gV0 + kv0, &lV[nb + c0 * 8]);
            async_ld16(gV1 + kv0, &lV[nb + c1 * 8]);
        }
        const bf16_t* lKc = lK + cur * 4096;
        const bf16_t* lVc = lV + cur * 4096;

        // ---- S^T: D[m = kv-local(32)][n = q(32)]
        bf16x8 kf[4];
#pragma unroll
        for (int c = 0; c < 4; ++c) kf[c] = *(const bf16x8*)&lKc[koff[c]];

        f32x16 st;
#pragma unroll
        for (int i = 0; i < 16; ++i) st[i] = 0.f;
        __builtin_amdgcn_s_setprio(1);
#pragma unroll
        for (int c = 0; c < 4; ++c)
            st = __builtin_amdgcn_mfma_f32_32x32x16_bf16(kf[c], qf[c], st, 0, 0, 0);
        __builtin_amdgcn_s_setprio(0);

        // ---- exp2 + pack: pk[g][r] = P[kv-local = 8g+4h+r][q = l31]
        bf16x4 pk[4];
#pragma unroll
        for (int g = 0; g < 4; ++g)
#pragma unroll
            for (int r = 0; r < 4; ++r)
                pk[g][r] = (bf16_t)__builtin_amdgcn_exp2f(st[g * 4 + r]);

        // ---- assemble PV A-frags via permlane32_swap:
        // pf[ck] = A[m = q = l31][k = kv-local 16ck + 8h + j]
        bf16x8 pf[2];
#pragma unroll
        for (int ck = 0; ck < 2; ++ck) {
            union { bf16x4 v; uint32_t d[2]; } ua, ub;
            ua.v = pk[2 * ck];
            ub.v = pk[2 * ck + 1];
            uint32_t a0 = ua.d[0], b0 = ub.d[0];
            uint32_t a1 = ua.d[1], b1 = ub.d[1];
            plswap(a0, b0);
            plswap(a1, b1);
            union { bf16x8 v; uint32_t d[4]; } up;
            up.d[0] = a0; up.d[1] = a1; up.d[2] = b0; up.d[3] = b1;
            pf[ck] = up.v;
        }

        // ---- PV + ones-column row-sum
        __builtin_amdgcn_s_setprio(1);
#pragma unroll
        for (int ck = 0; ck < 2; ++ck)
            acc_s = __builtin_amdgcn_mfma_f32_32x32x16_bf16(pf[ck], onef, acc_s, 0, 0, 0);
#pragma unroll
        for (int a = 0; a < 2; ++a)
#pragma unroll
            for (int ck = 0; ck < 2; ++ck) {
                bf16x8 vf = *(const bf16x8*)&lVc[voff[a][ck]];
                acc_o[a] = __builtin_amdgcn_mfma_f32_32x32x16_bf16(
                    pf[ck], vf, acc_o[a], 0, 0, 0);
            }
        __builtin_amdgcn_s_setprio(0);

        // ---- own DMA + LDS ops drained, then block rendezvous (one asm so
        // nothing is scheduled between the waits and the barrier).
        asm volatile("s_waitcnt vmcnt(0) lgkmcnt(0)\n\ts_barrier" ::: "memory");
        cur ^= 1;
    }

    // ---- epilogue: combine wk pairs through LDS (arena reused; loop's final
    // barrier guarantees all tile reads are done). Blob: 48 floats, stride 52.
    union F16 { f32x16 v; f32x4 q[4]; };
    float* blob = (float*)arena + ((size_t)(wq * 64 + lane)) * 52;

    if (wk) {
#pragma unroll
        for (int a = 0; a < 2; ++a) {
            F16 u; u.v = acc_o[a];
#pragma unroll
            for (int i = 0; i < 4; ++i)
                *(f32x4*)&blob[(a * 4 + i) * 4] = u.q[i];
        }
        F16 s; s.v = acc_s;
#pragma unroll
        for (int i = 0; i < 4; ++i)
            *(f32x4*)&blob[32 + i * 4] = s.q[i];
    }
    __syncthreads();
    if (!wk) {
#pragma unroll
        for (int a = 0; a < 2; ++a) {
            F16 u; u.v = acc_o[a];
#pragma unroll
            for (int i = 0; i < 4; ++i)
                u.q[i] += *(const f32x4*)&blob[(a * 4 + i) * 4];
            acc_o[a] = u.v;
        }
        F16 s; s.v = acc_s;
#pragma unroll
        for (int i = 0; i < 4; ++i)
            s.q[i] += *(const f32x4*)&blob[32 + i * 4];
        acc_s = s.v;

        // O / rowsum; 32x32 C-layout row = r + 8g + 4h, col = l31
#pragma unroll
        for (int g = 0; g < 4; ++g)
#pragma unroll
            for (int r = 0; r < 4; ++r) {
                const float inv = 1.0f / acc_s[g * 4 + r];
                const int row = b_ * SEQ + q0 + wq * 32 + (r + 8 * g + 4 * h);
                const size_t rb = (size_t)row * D_MODEL + hh * DHEAD + l31;
                Ob[rb]      = (bf16_t)(acc_o[0][g * 4 + r] * inv);
                Ob[rb + 32] = (bf16_t)(acc_o[1][g * 4 + r] * inv);
            }
    }
}

// ---------------------------------------------------------------------------
extern "C" void kernel_launch(void* const* d_in, const int* in_sizes, int n_in,
                              void* d_out, int out_size, void* d_ws, size_t ws_size,
                              hipStream_t stream)
{
    const float* x  = (const float*)d_in[0];
    const float* Wq = (const float*)d_in[1];
    const float* Wk = (const float*)d_in[2];
    const float* Wv = (const float*)d_in[3];
    const float* Wo = (const float*)d_in[4];
    float* out = (float*)d_out;

    const size_t wmat = (size_t)D_MODEL * D_MODEL;  // 1M elements
    const size_t mat  = (size_t)NROWS * D_MODEL;    // 4M elements
    bf16_t* Wqb = (bf16_t*)d_ws;
    bf16_t* Wkb = Wqb + wmat;
    bf16_t* Wvb = Wkb + wmat;
    bf16_t* Wob = Wvb + wmat;
    bf16_t* Xb  = Wob + wmat;
    bf16_t* Qb  = Xb + mat;
    bf16_t* Kb  = Qb + mat;
    bf16_t* Vt  = Kb + mat;                          // [bh][dh][s]
    bf16_t* Ab  = Qb;                                // alias (see k_attn)

    dim3 blk(256);
    k_cvt<<<dim3(4096), blk, 0, stream>>>(Wq, Wk, Wv, Wo, x, Wqb, Wkb, Wvb, Wob, Xb);
    k_gemm_qkv<<<dim3(32, 24), blk, 0, stream>>>(Xb, Wqb, Wkb, Wvb, Qb, Kb, Vt);
    k_attn<<<dim3(32, 32), blk, 0, stream>>>(Qb, Kb, Vt, Ab);
    k_gemm_out<<<dim3(32, 8), blk, 0, stream>>>(Ab, Wob, out);
}

// Round 5
// 183.724 us; speedup vs baseline: 1.0092x; 1.0092x over previous
//
#include <hip/hip_runtime.h>
#include <stdint.h>

typedef __bf16 bf16_t;
typedef __bf16 bf16x4 __attribute__((ext_vector_type(4)));
typedef __bf16 bf16x8 __attribute__((ext_vector_type(8)));
typedef float  f32x4  __attribute__((ext_vector_type(4)));
typedef float  f32x16 __attribute__((ext_vector_type(16)));

#define D_MODEL 1024
#define SEQ     2048
#define BATCH   2
#define NHEAD   16
#define DHEAD   64
#define NROWS   (BATCH*SEQ)   // 4096
#define LDT     72            // GEMM V-transpose buffer stride (16B-aligned)

// log2(e): folded into Q scale so attn uses v_exp_f32 (exp2) directly.
#define QSCALE  (0.125f * 1.4426950408889634f)

// async 16B global->LDS DMA (m97). LDS dest must be wave-uniform base + lane*16.
__device__ __forceinline__ void async_ld16(const bf16_t* g, bf16_t* l) {
    __builtin_amdgcn_global_load_lds(
        (const __attribute__((address_space(1))) uint32_t*)(uintptr_t)g,
        (__attribute__((address_space(3))) uint32_t*)(uintptr_t)l,
        16, 0, 0);
}

__device__ __forceinline__ bf16x8 cvt8(f32x4 lo, f32x4 hi) {
    bf16x8 o;
#pragma unroll
    for (int i = 0; i < 4; ++i) { o[i] = (bf16_t)lo[i]; o[4 + i] = (bf16_t)hi[i]; }
    return o;
}

// v_permlane32_swap_b32 a, b:  a' = {a[0:31], b[0:31]},  b' = {a[32:63], b[32:63]}
__device__ __forceinline__ void plswap(uint32_t& a, uint32_t& b) {
    asm("v_permlane32_swap_b32 %0, %1" : "+v"(a), "+v"(b));
}

// pack 2 f32 -> 1 dword of 2 bf16 (low = lo, high = hi). No builtin on gfx950.
__device__ __forceinline__ uint32_t cvtpk(float lo, float hi) {
    uint32_t r;
    asm("v_cvt_pk_bf16_f32 %0, %1, %2" : "=v"(r) : "v"(lo), "v"(hi));
    return r;
}

// ---------------------------------------------------------------------------
// f32 -> bf16 pre-convert of Wq,Wk,Wv,Wo (512 blocks each) + x (2048 blocks).
// ---------------------------------------------------------------------------
__global__ void __launch_bounds__(256)
k_cvt(const float* __restrict__ w0, const float* __restrict__ w1,
      const float* __restrict__ w2, const float* __restrict__ w3,
      const float* __restrict__ x,
      bf16_t* __restrict__ o0, bf16_t* __restrict__ o1,
      bf16_t* __restrict__ o2, bf16_t* __restrict__ o3,
      bf16_t* __restrict__ ox)
{
    const int blk = blockIdx.x;
    const float* s; bf16_t* d; int bi;
    if (blk < 2048) { s = x; d = ox; bi = blk; }
    else {
        const int t = blk - 2048, sel = t >> 9; bi = t & 511;
        s = (sel == 0) ? w0 : (sel == 1) ? w1 : (sel == 2) ? w2 : w3;
        d = (sel == 0) ? o0 : (sel == 1) ? o1 : (sel == 2) ? o2 : o3;
    }
    const size_t i = ((size_t)bi * 256 + threadIdx.x) * 8;
    *(bf16x8*)(d + i) = cvt8(*(const f32x4*)(s + i), *(const f32x4*)(s + i + 4));
}

// ---------------------------------------------------------------------------
// MT x 128 GEMM tile: Y = X @ W^T * oscale. A and B bf16. MT in {64,128}.
// Staging: global_load_lds width=16, 32-elem LDS rows, XOR-4 chunk swizzle.
// OUT_MODE: 0 = bf16 row-major; 1 = bf16 V^T [bh][dh][s] (MT=128 only);
//           2 = f32 row-major.
// ---------------------------------------------------------------------------
template <int OUT_MODE, int MT>
__device__ __forceinline__ void gemmT(bf16_t* __restrict__ smem,
                                      const bf16_t* __restrict__ X,
                                      const bf16_t* __restrict__ W,
                                      void* __restrict__ Yv,
                                      int m0, int n0, float oscale)
{
    constexpr int FM = MT / 32;        // A-frags (16-row) per wave
    bf16_t* lA = smem;                 // MT x 32
    bf16_t* lB = smem + MT * 32;       // 128 x 32

    const int tid  = threadIdx.x;
    const int lane = tid & 63;
    const int w    = tid >> 6;
    const int l15  = lane & 15;
    const int quad = lane >> 4;

    // B staging: 512 chunks, 2 per thread
    const int cB0 = tid, cB1 = tid + 256;
    const int rB0 = cB0 >> 2, rB1 = cB1 >> 2;
    const int kB0 = (cB0 & 3) ^ ((rB0 >> 1) & 3);
    const int kB1 = (cB1 & 3) ^ ((rB1 >> 1) & 3);
    const bf16_t* gB0 = W + (size_t)(n0 + rB0) * D_MODEL + kB0 * 8;
    const bf16_t* gB1 = W + (size_t)(n0 + rB1) * D_MODEL + kB1 * 8;

    // A staging: MT*4 chunks (MT=128: 2/thread, MT=64: 1/thread)
    const int cA0 = tid;
    const int rA0 = cA0 >> 2;
    const int kA0 = (cA0 & 3) ^ ((rA0 >> 1) & 3);
    const bf16_t* gA0 = X + (size_t)(m0 + rA0) * D_MODEL + kA0 * 8;
    const int cA1 = tid + 256;
    const int rA1 = cA1 >> 2;
    const int kA1 = (cA1 & 3) ^ ((rA1 >> 1) & 3);
    const bf16_t* gA1 = X + (size_t)(m0 + rA1) * D_MODEL + kA1 * 8;

    int am[FM], bn[4];
    const int mw = (w >> 1) * (MT / 2), nw = (w & 1) * 64;
#pragma unroll
    for (int i = 0; i < FM; ++i) {
        const int ra = mw + i * 16 + l15;
        am[i] = ra * 32 + (quad ^ ((ra >> 1) & 3)) * 8;
    }
#pragma unroll
    for (int i = 0; i < 4; ++i) {
        const int rb = nw + i * 16 + l15;
        bn[i] = rb * 32 + (quad ^ ((rb >> 1) & 3)) * 8;
    }

    f32x4 acc[FM][4];
#pragma unroll
    for (int i = 0; i < FM; ++i)
#pragma unroll
        for (int j = 0; j < 4; ++j) acc[i][j] = f32x4{0.f, 0.f, 0.f, 0.f};

    for (int k0 = 0; k0 < D_MODEL; k0 += 32) {
        __syncthreads();
        async_ld16(gA0 + k0, &lA[cA0 * 8]);
        if constexpr (MT == 128) async_ld16(gA1 + k0, &lA[cA1 * 8]);
        async_ld16(gB0 + k0, &lB[cB0 * 8]);
        async_ld16(gB1 + k0, &lB[cB1 * 8]);
        __syncthreads();

        bf16x8 af[FM], bfr[4];
#pragma unroll
        for (int i = 0; i < FM; ++i) af[i] = *(const bf16x8*)&lA[am[i]];
#pragma unroll
        for (int i = 0; i < 4; ++i) bfr[i] = *(const bf16x8*)&lB[bn[i]];
#pragma unroll
        for (int mi = 0; mi < FM; ++mi)
#pragma unroll
            for (int ni = 0; ni < 4; ++ni)
                acc[mi][ni] = __builtin_amdgcn_mfma_f32_16x16x32_bf16(
                    af[mi], bfr[ni], acc[mi][ni], 0, 0, 0);
    }

    if constexpr (OUT_MODE == 1) {
        bf16_t* lT = smem;                        // 128 cols x LDT
#pragma unroll
        for (int h0 = 0; h0 < 2; ++h0) {
            __syncthreads();
            if ((w >> 1) == h0) {
#pragma unroll
                for (int mi = 0; mi < FM; ++mi)
#pragma unroll
                    for (int ni = 0; ni < 4; ++ni) {
                        bf16x4 pk;
#pragma unroll
                        for (int r = 0; r < 4; ++r)
                            pk[r] = (bf16_t)(acc[mi][ni][r] * oscale);
                        const int col = nw + ni * 16 + l15;
                        *(bf16x4*)&lT[col * LDT + mi * 16 + quad * 4] = pk;
                    }
            }
            __syncthreads();
            const int col = tid & 127;
            const int seg = tid >> 7;
            const int brow = m0 + h0 * 64;
            const int b = brow >> 11, sb = brow & 2047;
            const int cg = n0 + col;              // h*64+dh
            bf16_t* dst = (bf16_t*)Yv +
                ((size_t)((b << 4) | (cg >> 6)) * 64 + (cg & 63)) * SEQ + sb;
#pragma unroll
            for (int u = 0; u < 4; ++u)
                *(bf16x8*)(dst + seg * 32 + u * 8) =
                    *(const bf16x8*)&lT[col * LDT + seg * 32 + u * 8];
        }
    } else {
        // C/D layout col = lane&15, row = quad*4 + reg (m89-verified)
#pragma unroll
        for (int mi = 0; mi < FM; ++mi)
#pragma unroll
            for (int ni = 0; ni < 4; ++ni)
#pragma unroll
                for (int r = 0; r < 4; ++r) {
                    const int row = m0 + mw + mi * 16 + quad * 4 + r;
                    const int col = n0 + nw + ni * 16 + l15;
                    const float vv = acc[mi][ni][r] * oscale;
                    if constexpr (OUT_MODE == 0)
                        ((bf16_t*)Yv)[(size_t)row * D_MODEL + col] = (bf16_t)vv;
                    else
                        ((float*)Yv)[(size_t)row * D_MODEL + col] = vv;
                }
    }
}

// 768 blocks. XCD swizzle (id%8 = hw XCD): XCD k processes y' in {3k..3k+2}
// -> 3 W-panels (768KB) L2-resident per XCD; X rows streamed/shared.
__global__ void __launch_bounds__(256, 3)
k_gemm_qkv(const bf16_t* __restrict__ X,
           const bf16_t* __restrict__ Wq, const bf16_t* __restrict__ Wk,
           const bf16_t* __restrict__ Wv,
           bf16_t* __restrict__ Qb, bf16_t* __restrict__ Kb, bf16_t* __restrict__ Vt)
{
    __shared__ __align__(16) bf16_t smem[128 * LDT];   // 18432 B
    const int id = blockIdx.x + 32 * blockIdx.y;       // 0..767
    const int s  = (id & 7) * 96 + (id >> 3);          // bijective (768%8==0)
    const int m0 = (s & 31) * 128;
    const int yp = s >> 5;                             // 0..23
    const int sel = yp >> 3;                           // 0=Q 1=K 2=V
    const int n0  = (yp & 7) * 128;
    if (sel == 0)      gemmT<0,128>(smem, X, Wq, Qb, m0, n0, QSCALE);
    else if (sel == 1) gemmT<0,128>(smem, X, Wk, Kb, m0, n0, 1.0f);
    else               gemmT<1,128>(smem, X, Wv, Vt, m0, n0, 1.0f);
}

// Round-5: MT=64 tiles -> 512 blocks = 2 blocks/CU (was 256 = 1/CU,
// latency-starved). XCD swizzle: XCD k gets n-tile k -> W-panel L2-resident.
__global__ void __launch_bounds__(256, 2)
k_gemm_out(const bf16_t* __restrict__ X, const bf16_t* __restrict__ W,
           float* __restrict__ Y)
{
    __shared__ __align__(16) bf16_t smem[64 * 32 + 128 * 32];  // 12 KiB
    const int id = blockIdx.x + 64 * blockIdx.y;       // 0..511
    const int s  = (id & 7) * 64 + (id >> 3);          // bijective (512%8==0)
    const int m0 = (s & 63) * 64;
    const int n0 = (s >> 6) * 128;
    gemmT<2,64>(smem, X, W, Y, m0, n0, 1.0f);
}

// ---------------------------------------------------------------------------
// Attention, Q-tile 128 (r2 topology: best DS amortization). 4 waves, 2x2:
// wq = 64-row q-strip, wk = 32-row kv-half. Per wave-iter: 4 K + 4 V
// ds_read_b128 serving 2 qh each, 20 MFMA, 32 exp2.
// Round-5 changes:
//  * T4 counted vmcnt: triple-buffered K/V (prefetch distance 2); end-of-iter
//    waits vmcnt(4) (next tile's 4 loads complete, the tile-after's 4 stay in
//    flight) instead of a full drain. Race audit: buf[(t+2)%3] overwritten at
//    iter t was last read at iter t-1, whose reads were drained (lgkmcnt(0) by
//    every wave) before the t-1 barrier. FIFO vmcnt (m135) makes vmcnt(4)
//    guarantee the older tile's 4 loads have landed.
//  * VALU diet: v_cvt_pk_bf16_f32 packing (16 cvt_pk vs 32 cvt + 32 inserts);
//    QK accumulator initialized via a hoisted zero C-operand (no per-iter
//    v_mov x16 x2qh).
//  * XCD swizzle: 4 bh per XCD -> K+V (2MB) L2-resident for that XCD's 16
//    q-tile blocks; staging DMA becomes L2-hit.
// Row-sum via ones-column MFMA (acc_s layout == acc_o). Partner h-exchange
// via v_permlane32_swap_b32. Epilogue combines wk pairs through reused LDS.
// Ob may alias Qb (Q read to regs up-front; block-disjoint slices).
// ---------------------------------------------------------------------------
__global__ void __launch_bounds__(256, 2)
k_attn(const bf16_t* __restrict__ Qb, const bf16_t* __restrict__ Kb,
       const bf16_t* __restrict__ Vt, bf16_t* __restrict__ Ob)
{
    // arena: main loop lK[3][4096]+lV[3][4096] bf16 = 48 KiB;
    // epilogue reuses it as 2 x 64 blobs of 96 floats (stride 100 -> 50 KiB).
    __shared__ __align__(16) char arena[51200];
    bf16_t* lK = (bf16_t*)arena;               // [3][64*64] swizzled chunks
    bf16_t* lV = (bf16_t*)(arena + 24576);     // [3][64*64] swizzled chunks

    const int tid  = threadIdx.x;
    const int lane = tid & 63;
    const int w    = tid >> 6;
    const int wq   = w >> 1;      // q-strip (64 rows)
    const int wk   = w & 1;       // kv-half (32 rows)
    const int l31  = lane & 31;
    const int h    = lane >> 5;

    // XCD swizzle: dispatch i -> XCD i%8; give XCD k the 4 bh {4k..4k+3}.
    const int i_  = blockIdx.x + 32 * blockIdx.y;      // 0..511
    const int bh  = 4 * (i_ & 7) + ((i_ >> 3) & 3);    // bijective
    const int q0  = (i_ >> 5) * 128;
    const int b_ = bh >> 4, hh = bh & 15;

    const size_t base = (size_t)b_ * SEQ * D_MODEL + (size_t)hh * DHEAD;
    const bf16_t* Qp = Qb + base;
    const bf16_t* Kp = Kb + base;
    const bf16_t* Vp = Vt + (size_t)bh * DHEAD * SEQ;   // [dh][s]

    // Q B-frags in regs: B[n = q = l31][k = dh-local h*8+j], chunk c = dh/16
    bf16x8 qf[2][4];
#pragma unroll
    for (int qh = 0; qh < 2; ++qh) {
        const int qrow = q0 + wq * 64 + qh * 32 + l31;
#pragma unroll
        for (int c = 0; c < 4; ++c)
            qf[qh][c] = *(const bf16x8*)&Qp[(size_t)qrow * D_MODEL + c * 16 + h * 8];
    }

    // staging: 512 chunks per tile, 2 per thread; chunk c -> row c>>3, slot
    // c&7, global chunk g = (c&7) ^ (row&7). Note (r0+32)&7 == r0&7.
    const int c0 = tid, c1 = tid + 256;
    const int r0 = c0 >> 3, g0 = (c0 & 7) ^ (r0 & 7);
    const int r1 = r0 + 32;
    const bf16_t* gK0 = Kp + (size_t)r0 * D_MODEL + g0 * 8;
    const bf16_t* gK1 = Kp + (size_t)r1 * D_MODEL + g0 * 8;
    const bf16_t* gV0 = Vp + (size_t)r0 * SEQ + g0 * 8;
    const bf16_t* gV1 = Vp + (size_t)r1 * SEQ + g0 * 8;

    // fragment read offsets (row-dependent XOR slot)
    int koff[4], voff[2][2];
#pragma unroll
    for (int c = 0; c < 4; ++c) {
        const int row = wk * 32 + l31;               // kv row (wave's half)
        koff[c] = row * 64 + (((2 * c + h) ^ (row & 7)) * 8);
    }
#pragma unroll
    for (int a = 0; a < 2; ++a)
#pragma unroll
        for (int ck = 0; ck < 2; ++ck) {
            const int row = a * 32 + l31;            // dh row
            const int ch  = 4 * wk + 2 * ck + h;     // kv chunk within row
            voff[a][ck] = row * 64 + ((ch ^ (row & 7)) * 8);
        }

    bf16x8 onef;
#pragma unroll
    for (int i = 0; i < 8; ++i) onef[i] = (bf16_t)1.0f;

    f32x16 fz;                     // hoisted zero C-operand for QK MFMA
#pragma unroll
    for (int i = 0; i < 16; ++i) fz[i] = 0.f;

    f32x16 acc_o[2][2];            // [qh][a]  D[m=q][n=dh]
    f32x16 acc_s[2];               // [qh]     rowsum (ones-column PV)
#pragma unroll
    for (int qh = 0; qh < 2; ++qh) {
#pragma unroll
        for (int i = 0; i < 16; ++i) {
            acc_o[qh][0][i] = 0.f; acc_o[qh][1][i] = 0.f; acc_s[qh][i] = 0.f;
        }
    }

    auto STAGE = [&](int tile, int buf) {
        const size_t kv0 = (size_t)tile * 64;
        bf16_t* dK = lK + buf * 4096;
        bf16_t* dV = lV + buf * 4096;
        async_ld16(gK0 + kv0 * D_MODEL, &dK[c0 * 8]);
        async_ld16(gK1 + kv0 * D_MODEL, &dK[c1 * 8]);
        async_ld16(gV0 + kv0, &dV[c0 * 8]);
        async_ld16(gV1 + kv0, &dV[c1 * 8]);
    };

    // ---- prologue: stage tiles 0,1; wait for tile 0 only (vmcnt(4))
    STAGE(0, 0);
    STAGE(1, 1);
    asm volatile("s_waitcnt vmcnt(4)\n\ts_barrier" ::: "memory");

    int cb = 0;                    // current buffer = t % 3
    const int NT = SEQ / 64;       // 32
    for (int t = 0; t < NT; ++t) {
        // ---- issue tile t+2 into buf (t+2)%3; 2-iter window to land
        if (t + 2 < NT) STAGE(t + 2, cb == 0 ? 2 : cb - 1);
        const bf16_t* lKc = lK + cb * 4096;
        const bf16_t* lVc = lV + cb * 4096;

        // ---- S^T: D[m = kv-local(32)][n = q(32)], shared kf across both qh
        bf16x8 kf[4];
#pragma unroll
        for (int c = 0; c < 4; ++c) kf[c] = *(const bf16x8*)&lKc[koff[c]];

        f32x16 st[2];
        __builtin_amdgcn_s_setprio(1);
#pragma unroll
        for (int qh = 0; qh < 2; ++qh) {
            st[qh] = __builtin_amdgcn_mfma_f32_32x32x16_bf16(
                kf[0], qf[qh][0], fz, 0, 0, 0);
#pragma unroll
            for (int c = 1; c < 4; ++c)
                st[qh] = __builtin_amdgcn_mfma_f32_32x32x16_bf16(
                    kf[c], qf[qh][c], st[qh], 0, 0, 0);
        }
        __builtin_amdgcn_s_setprio(0);

        // ---- exp2 + cvt_pk: pd[qh][g] = two dwords of 4 bf16 exp values,
        // element r of group g = P[kv-local = 8g+4h+r][q = l31]
        uint32_t pd[2][4][2];
#pragma unroll
        for (int qh = 0; qh < 2; ++qh)
#pragma unroll
            for (int g = 0; g < 4; ++g) {
                pd[qh][g][0] = cvtpk(__builtin_amdgcn_exp2f(st[qh][g * 4 + 0]),
                                     __builtin_amdgcn_exp2f(st[qh][g * 4 + 1]));
                pd[qh][g][1] = cvtpk(__builtin_amdgcn_exp2f(st[qh][g * 4 + 2]),
                                     __builtin_amdgcn_exp2f(st[qh][g * 4 + 3]));
            }

        // ---- assemble PV A-frags via permlane32_swap:
        // pf[qh][ck] = A[m = q = l31][k = kv-local 16ck + 8h + j]
        bf16x8 pf[2][2];
#pragma unroll
        for (int qh = 0; qh < 2; ++qh)
#pragma unroll
            for (int ck = 0; ck < 2; ++ck) {
                uint32_t a0 = pd[qh][2 * ck][0],     b0 = pd[qh][2 * ck + 1][0];
                uint32_t a1 = pd[qh][2 * ck][1],     b1 = pd[qh][2 * ck + 1][1];
                plswap(a0, b0);
                plswap(a1, b1);
                union { bf16x8 v; uint32_t d[4]; } up;
                up.d[0] = a0; up.d[1] = a1; up.d[2] = b0; up.d[3] = b1;
                pf[qh][ck] = up.v;
            }

        // ---- PV + ones-column row-sum
        __builtin_amdgcn_s_setprio(1);
#pragma unroll
        for (int qh = 0; qh < 2; ++qh)
#pragma unroll
            for (int ck = 0; ck < 2; ++ck)
                acc_s[qh] = __builtin_amdgcn_mfma_f32_32x32x16_bf16(
                    pf[qh][ck], onef, acc_s[qh], 0, 0, 0);
#pragma unroll
        for (int a = 0; a < 2; ++a)
#pragma unroll
            for (int ck = 0; ck < 2; ++ck) {
                bf16x8 vf = *(const bf16x8*)&lVc[voff[a][ck]];
#pragma unroll
                for (int qh = 0; qh < 2; ++qh)
                    acc_o[qh][a] = __builtin_amdgcn_mfma_f32_32x32x16_bf16(
                        pf[qh][ck], vf, acc_o[qh][a], 0, 0, 0);
            }
        __builtin_amdgcn_s_setprio(0);

        // ---- counted wait + rendezvous (one asm: nothing scheduled between).
        // vmcnt(4): tile t+1's loads landed, tile t+2's may stay in flight.
        // lgkmcnt(0): all my reads of buf t returned -> after the barrier no
        // wave can observe a stale read while buf t is overwritten next iter.
        if (t + 2 < NT)
            asm volatile("s_waitcnt vmcnt(4) lgkmcnt(0)\n\ts_barrier" ::: "memory");
        else
            asm volatile("s_waitcnt vmcnt(0) lgkmcnt(0)\n\ts_barrier" ::: "memory");
        cb = (cb == 2) ? 0 : cb + 1;
    }

    // ---- epilogue: combine wk pairs through LDS (arena reused; loop's final
    // barrier guarantees all tile reads and DMAs are done).
    union F16 { f32x16 v; f32x4 q[4]; };
    float* blob = (float*)arena + ((size_t)(wq * 64 + lane)) * 100;  // 400B stride

    if (wk) {
#pragma unroll
        for (int qh = 0; qh < 2; ++qh) {
#pragma unroll
            for (int a = 0; a < 2; ++a) {
                F16 u; u.v = acc_o[qh][a];
#pragma unroll
                for (int i = 0; i < 4; ++i)
                    *(f32x4*)&blob[(qh * 8 + a * 4 + i) * 4] = u.q[i];
            }
            F16 s; s.v = acc_s[qh];
#pragma unroll
            for (int i = 0; i < 4; ++i)
                *(f32x4*)&blob[64 + (qh * 4 + i) * 4] = s.q[i];
        }
    }
    __syncthreads();
    if (!wk) {
#pragma unroll
        for (int qh = 0; qh < 2; ++qh) {
#pragma unroll
            for (int a = 0; a < 2; ++a) {
                F16 u; u.v = acc_o[qh][a];
#pragma unroll
                for (int i = 0; i < 4; ++i)
                    u.q[i] += *(const f32x4*)&blob[(qh * 8 + a * 4 + i) * 4];
                acc_o[qh][a] = u.v;
            }
            F16 s; s.v = acc_s[qh];
#pragma unroll
            for (int i = 0; i < 4; ++i)
                s.q[i] += *(const f32x4*)&blob[64 + (qh * 4 + i) * 4];
            acc_s[qh] = s.v;
        }

        // O / rowsum; 32x32 C-layout row = r + 8g + 4h, col = l31
#pragma unroll
        for (int qh = 0; qh < 2; ++qh)
#pragma unroll
            for (int g = 0; g < 4; ++g)
#pragma unroll
                for (int r = 0; r < 4; ++r) {
                    const float inv = 1.0f / acc_s[qh][g * 4 + r];
                    const int row = b_ * SEQ + q0 + wq * 64 + qh * 32 + (r + 8 * g + 4 * h);
                    const size_t rb = (size_t)row * D_MODEL + hh * DHEAD + l31;
                    Ob[rb]      = (bf16_t)(acc_o[qh][0][g * 4 + r] * inv);
                    Ob[rb + 32] = (bf16_t)(acc_o[qh][1][g * 4 + r] * inv);
                }
    }
}

// ---------------------------------------------------------------------------
extern "C" void kernel_launch(void* const* d_in, const int* in_sizes, int n_in,
                              void* d_out, int out_size, void* d_ws, size_t ws_size,
                              hipStream_t stream)
{
    const float* x  = (const float*)d_in[0];
    const float* Wq = (const float*)d_in[1];
    const float* Wk = (const float*)d_in[2];
    const float* Wv = (const float*)d_in[3];
    const float* Wo = (const float*)d_in[4];
    float* out = (float*)d_out;

    const size_t wmat = (size_t)D_MODEL * D_MODEL;  // 1M elements
    const size_t mat  = (size_t)NROWS * D_MODEL;    // 4M elements
    bf16_t* Wqb = (bf16_t*)d_ws;
    bf16_t* Wkb = Wqb + wmat;
    bf16_t* Wvb = Wkb + wmat;
    bf16_t* Wob = Wvb + wmat;
    bf16_t* Xb  = Wob + wmat;
    bf16_t* Qb  = Xb + mat;
    bf16_t* Kb  = Qb + mat;
    bf16_t* Vt  = Kb + mat;                          // [bh][dh][s]
    bf16_t* Ab  = Qb;                                // alias (see k_attn)

    dim3 blk(256);
    k_cvt<<<dim3(4096), blk, 0, stream>>>(Wq, Wk, Wv, Wo, x, Wqb, Wkb, Wvb, Wob, Xb);
    k_gemm_qkv<<<dim3(32, 24), blk, 0, stream>>>(Xb, Wqb, Wkb, Wvb, Qb, Kb, Vt);
    k_attn<<<dim3(32, 16), blk, 0, stream>>>(Qb, Kb, Vt, Ab);
    k_gemm_out<<<dim3(64, 8), blk, 0, stream>>>(Ab, Wob, out);
}

// Round 6
// 182.984 us; speedup vs baseline: 1.0133x; 1.0040x over previous
//
#include <hip/hip_runtime.h>
#include <stdint.h>

typedef __bf16 bf16_t;
typedef __bf16 bf16x4 __attribute__((ext_vector_type(4)));
typedef __bf16 bf16x8 __attribute__((ext_vector_type(8)));
typedef float  f32x4  __attribute__((ext_vector_type(4)));
typedef float  f32x16 __attribute__((ext_vector_type(16)));

#define D_MODEL 1024
#define SEQ     2048
#define BATCH   2
#define NHEAD   16
#define DHEAD   64
#define NROWS   (BATCH*SEQ)   // 4096
#define LDT     72            // GEMM V-transpose buffer stride (16B-aligned)

// log2(e): folded into Q scale so attn uses v_exp_f32 (exp2) directly.
#define QSCALE  (0.125f * 1.4426950408889634f)

// async 16B global->LDS DMA (m97). LDS dest must be wave-uniform base + lane*16.
__device__ __forceinline__ void async_ld16(const bf16_t* g, bf16_t* l) {
    __builtin_amdgcn_global_load_lds(
        (const __attribute__((address_space(1))) uint32_t*)(uintptr_t)g,
        (__attribute__((address_space(3))) uint32_t*)(uintptr_t)l,
        16, 0, 0);
}

__device__ __forceinline__ bf16x8 cvt8(f32x4 lo, f32x4 hi) {
    bf16x8 o;
#pragma unroll
    for (int i = 0; i < 4; ++i) { o[i] = (bf16_t)lo[i]; o[4 + i] = (bf16_t)hi[i]; }
    return o;
}

// v_permlane32_swap_b32 a, b:  a' = {a[0:31], b[0:31]},  b' = {a[32:63], b[32:63]}
__device__ __forceinline__ void plswap(uint32_t& a, uint32_t& b) {
    asm("v_permlane32_swap_b32 %0, %1" : "+v"(a), "+v"(b));
}

// ---------------------------------------------------------------------------
// f32 -> bf16 pre-convert of Wq,Wk,Wv,Wo (512 blocks each) + x (2048 blocks).
// ---------------------------------------------------------------------------
__global__ void __launch_bounds__(256)
k_cvt(const float* __restrict__ w0, const float* __restrict__ w1,
      const float* __restrict__ w2, const float* __restrict__ w3,
      const float* __restrict__ x,
      bf16_t* __restrict__ o0, bf16_t* __restrict__ o1,
      bf16_t* __restrict__ o2, bf16_t* __restrict__ o3,
      bf16_t* __restrict__ ox)
{
    const int blk = blockIdx.x;
    const float* s; bf16_t* d; int bi;
    if (blk < 2048) { s = x; d = ox; bi = blk; }
    else {
        const int t = blk - 2048, sel = t >> 9; bi = t & 511;
        s = (sel == 0) ? w0 : (sel == 1) ? w1 : (sel == 2) ? w2 : w3;
        d = (sel == 0) ? o0 : (sel == 1) ? o1 : (sel == 2) ? o2 : o3;
    }
    const size_t i = ((size_t)bi * 256 + threadIdx.x) * 8;
    *(bf16x8*)(d + i) = cvt8(*(const f32x4*)(s + i), *(const f32x4*)(s + i + 4));
}

// ---------------------------------------------------------------------------
// MT x 128 GEMM tile: Y = X @ W^T * oscale. A and B bf16. MT in {64,128}.
// Staging: global_load_lds width=16, 32-elem LDS rows, XOR-4 chunk swizzle.
// OUT_MODE: 0 = bf16 row-major; 1 = bf16 V^T [bh][dh][s] (MT=128 only);
//           2 = f32 row-major.
// ---------------------------------------------------------------------------
template <int OUT_MODE, int MT>
__device__ __forceinline__ void gemmT(bf16_t* __restrict__ smem,
                                      const bf16_t* __restrict__ X,
                                      const bf16_t* __restrict__ W,
                                      void* __restrict__ Yv,
                                      int m0, int n0, float oscale)
{
    constexpr int FM = MT / 32;        // A-frags (16-row) per wave
    bf16_t* lA = smem;                 // MT x 32
    bf16_t* lB = smem + MT * 32;       // 128 x 32

    const int tid  = threadIdx.x;
    const int lane = tid & 63;
    const int w    = tid >> 6;
    const int l15  = lane & 15;
    const int quad = lane >> 4;

    // B staging: 512 chunks, 2 per thread
    const int cB0 = tid, cB1 = tid + 256;
    const int rB0 = cB0 >> 2, rB1 = cB1 >> 2;
    const int kB0 = (cB0 & 3) ^ ((rB0 >> 1) & 3);
    const int kB1 = (cB1 & 3) ^ ((rB1 >> 1) & 3);
    const bf16_t* gB0 = W + (size_t)(n0 + rB0) * D_MODEL + kB0 * 8;
    const bf16_t* gB1 = W + (size_t)(n0 + rB1) * D_MODEL + kB1 * 8;

    // A staging: MT*4 chunks (MT=128: 2/thread, MT=64: 1/thread)
    const int cA0 = tid;
    const int rA0 = cA0 >> 2;
    const int kA0 = (cA0 & 3) ^ ((rA0 >> 1) & 3);
    const bf16_t* gA0 = X + (size_t)(m0 + rA0) * D_MODEL + kA0 * 8;
    const int cA1 = tid + 256;
    const int rA1 = cA1 >> 2;
    const int kA1 = (cA1 & 3) ^ ((rA1 >> 1) & 3);
    const bf16_t* gA1 = X + (size_t)(m0 + rA1) * D_MODEL + kA1 * 8;

    int am[FM], bn[4];
    const int mw = (w >> 1) * (MT / 2), nw = (w & 1) * 64;
#pragma unroll
    for (int i = 0; i < FM; ++i) {
        const int ra = mw + i * 16 + l15;
        am[i] = ra * 32 + (quad ^ ((ra >> 1) & 3)) * 8;
    }
#pragma unroll
    for (int i = 0; i < 4; ++i) {
        const int rb = nw + i * 16 + l15;
        bn[i] = rb * 32 + (quad ^ ((rb >> 1) & 3)) * 8;
    }

    f32x4 acc[FM][4];
#pragma unroll
    for (int i = 0; i < FM; ++i)
#pragma unroll
        for (int j = 0; j < 4; ++j) acc[i][j] = f32x4{0.f, 0.f, 0.f, 0.f};

    for (int k0 = 0; k0 < D_MODEL; k0 += 32) {
        __syncthreads();
        async_ld16(gA0 + k0, &lA[cA0 * 8]);
        if constexpr (MT == 128) async_ld16(gA1 + k0, &lA[cA1 * 8]);
        async_ld16(gB0 + k0, &lB[cB0 * 8]);
        async_ld16(gB1 + k0, &lB[cB1 * 8]);
        __syncthreads();

        bf16x8 af[FM], bfr[4];
#pragma unroll
        for (int i = 0; i < FM; ++i) af[i] = *(const bf16x8*)&lA[am[i]];
#pragma unroll
        for (int i = 0; i < 4; ++i) bfr[i] = *(const bf16x8*)&lB[bn[i]];
#pragma unroll
        for (int mi = 0; mi < FM; ++mi)
#pragma unroll
            for (int ni = 0; ni < 4; ++ni)
                acc[mi][ni] = __builtin_amdgcn_mfma_f32_16x16x32_bf16(
                    af[mi], bfr[ni], acc[mi][ni], 0, 0, 0);
    }

    if constexpr (OUT_MODE == 1) {
        bf16_t* lT = smem;                        // 128 cols x LDT
#pragma unroll
        for (int h0 = 0; h0 < 2; ++h0) {
            __syncthreads();
            if ((w >> 1) == h0) {
#pragma unroll
                for (int mi = 0; mi < FM; ++mi)
#pragma unroll
                    for (int ni = 0; ni < 4; ++ni) {
                        bf16x4 pk;
#pragma unroll
                        for (int r = 0; r < 4; ++r)
                            pk[r] = (bf16_t)(acc[mi][ni][r] * oscale);
                        const int col = nw + ni * 16 + l15;
                        *(bf16x4*)&lT[col * LDT + mi * 16 + quad * 4] = pk;
                    }
            }
            __syncthreads();
            const int col = tid & 127;
            const int seg = tid >> 7;
            const int brow = m0 + h0 * 64;
            const int b = brow >> 11, sb = brow & 2047;
            const int cg = n0 + col;              // h*64+dh
            bf16_t* dst = (bf16_t*)Yv +
                ((size_t)((b << 4) | (cg >> 6)) * 64 + (cg & 63)) * SEQ + sb;
#pragma unroll
            for (int u = 0; u < 4; ++u)
                *(bf16x8*)(dst + seg * 32 + u * 8) =
                    *(const bf16x8*)&lT[col * LDT + seg * 32 + u * 8];
        }
    } else {
        // C/D layout col = lane&15, row = quad*4 + reg (m89-verified)
#pragma unroll
        for (int mi = 0; mi < FM; ++mi)
#pragma unroll
            for (int ni = 0; ni < 4; ++ni)
#pragma unroll
                for (int r = 0; r < 4; ++r) {
                    const int row = m0 + mw + mi * 16 + quad * 4 + r;
                    const int col = n0 + nw + ni * 16 + l15;
                    const float vv = acc[mi][ni][r] * oscale;
                    if constexpr (OUT_MODE == 0)
                        ((bf16_t*)Yv)[(size_t)row * D_MODEL + col] = (bf16_t)vv;
                    else
                        ((float*)Yv)[(size_t)row * D_MODEL + col] = vv;
                }
    }
}

// 768 blocks. XCD swizzle (id%8 = hw XCD): XCD k processes y' in {3k..3k+2}
// -> 3 W-panels (768KB) L2-resident per XCD; X rows streamed/shared.
__global__ void __launch_bounds__(256, 3)
k_gemm_qkv(const bf16_t* __restrict__ X,
           const bf16_t* __restrict__ Wq, const bf16_t* __restrict__ Wk,
           const bf16_t* __restrict__ Wv,
           bf16_t* __restrict__ Qb, bf16_t* __restrict__ Kb, bf16_t* __restrict__ Vt)
{
    __shared__ __align__(16) bf16_t smem[128 * LDT];   // 18432 B
    const int id = blockIdx.x + 32 * blockIdx.y;       // 0..767
    const int s  = (id & 7) * 96 + (id >> 3);          // bijective (768%8==0)
    const int m0 = (s & 31) * 128;
    const int yp = s >> 5;                             // 0..23
    const int sel = yp >> 3;                           // 0=Q 1=K 2=V
    const int n0  = (yp & 7) * 128;
    if (sel == 0)      gemmT<0,128>(smem, X, Wq, Qb, m0, n0, QSCALE);
    else if (sel == 1) gemmT<0,128>(smem, X, Wk, Kb, m0, n0, 1.0f);
    else               gemmT<1,128>(smem, X, Wv, Vt, m0, n0, 1.0f);
}

// MT=64 tiles -> 512 blocks = 2 blocks/CU. XCD swizzle: XCD k gets n-tile k.
__global__ void __launch_bounds__(256, 2)
k_gemm_out(const bf16_t* __restrict__ X, const bf16_t* __restrict__ W,
           float* __restrict__ Y)
{
    __shared__ __align__(16) bf16_t smem[64 * 32 + 128 * 32];  // 12 KiB
    const int id = blockIdx.x + 64 * blockIdx.y;       // 0..511
    const int s  = (id & 7) * 64 + (id >> 3);          // bijective (512%8==0)
    const int m0 = (s & 63) * 64;
    const int n0 = (s >> 6) * 128;
    gemmT<2,64>(smem, X, W, Y, m0, n0, 1.0f);
}

// ---------------------------------------------------------------------------
// Attention, Q-tile 128, r2 topology (best: 48.6 us). 4 waves, 2x2 split:
// wq = 64-row q-strip, wk = 32-row kv-half.
// Round-6 single change: KVBLK = 128 as TWO independent 64-kv sub-chains per
// barrier iteration. r2's pipes (MFMA 35 + VALU 34 + DS 28 ~= wall) are
// serialized by the per-wave chain QK->exp->pack->PV; two chains give the
// wave ILP so exp/pack(u0) issues under QK(u1) execution and exp/pack(u1)
// under PV(u0) (within-wave MFMA-shadow issue). Per-kv-row DS reads, MFMA
// and exp counts unchanged; barriers halve (32 -> 16); staging window
// doubles. Sync invariants identical to r2: stage next iter at top, one
// fused vmcnt(0)+lgkmcnt(0)+s_barrier at bottom (single asm, memory
// clobber). No cvt_pk asm (m240: hurts), no XCD swizzle (L3-fit), no
// counted vmcnt (T4 needs 8-phase role split).
// Ob may alias Qb (Q read to regs up-front; block-disjoint slices).
// ---------------------------------------------------------------------------
__global__ void __launch_bounds__(256, 2)
k_attn(const bf16_t* __restrict__ Qb, const bf16_t* __restrict__ Kb,
       const bf16_t* __restrict__ Vt, bf16_t* __restrict__ Ob)
{
    // arena: main loop 2 buf x {K[2][4096] V[2][4096]} bf16 = 64 KiB;
    // epilogue reuses it as 2 x 64 blobs of 96 floats (stride 100, 50 KiB).
    __shared__ __align__(16) char arena[65536];
    bf16_t* lKV = (bf16_t*)arena;   // buf stride 16384 elems:
                                    //   K sub-u at +u*4096, V sub-u at +8192+u*4096

    const int tid  = threadIdx.x;
    const int lane = tid & 63;
    const int w    = tid >> 6;
    const int wq   = w >> 1;      // q-strip (64 rows)
    const int wk   = w & 1;       // kv-half (32 rows within each 64-sub)
    const int l31  = lane & 31;
    const int h    = lane >> 5;

    const int bh = blockIdx.x;    // 0..31  (plain r2 mapping)
    const int b_ = bh >> 4, hh = bh & 15;
    const int q0 = blockIdx.y * 128;

    const size_t base = (size_t)b_ * SEQ * D_MODEL + (size_t)hh * DHEAD;
    const bf16_t* Qp = Qb + base;
    const bf16_t* Kp = Kb + base;
    const bf16_t* Vp = Vt + (size_t)bh * DHEAD * SEQ;   // [dh][s]

    // Q B-frags in regs: B[n = q = l31][k = dh-local h*8+j], chunk c = dh/16
    bf16x8 qf[2][4];
#pragma unroll
    for (int qh = 0; qh < 2; ++qh) {
        const int qrow = q0 + wq * 64 + qh * 32 + l31;
#pragma unroll
        for (int c = 0; c < 4; ++c)
            qf[qh][c] = *(const bf16x8*)&Qp[(size_t)qrow * D_MODEL + c * 16 + h * 8];
    }

    // staging: per 64-sub, 512 chunks, 2 per thread; chunk c -> row c>>3,
    // slot c&7, global chunk g = (c&7) ^ (row&7). Note (r0+32)&7 == r0&7.
    const int c0 = tid, c1 = tid + 256;
    const int r0 = c0 >> 3, g0 = (c0 & 7) ^ (r0 & 7);
    const int r1 = r0 + 32;
    const bf16_t* gK0 = Kp + (size_t)r0 * D_MODEL + g0 * 8;
    const bf16_t* gK1 = Kp + (size_t)r1 * D_MODEL + g0 * 8;
    const bf16_t* gV0 = Vp + (size_t)r0 * SEQ + g0 * 8;
    const bf16_t* gV1 = Vp + (size_t)r1 * SEQ + g0 * 8;

    // fragment read offsets within a 4096-elem sub-slot (row-dep XOR slot)
    int koff[4], voff[2][2];
#pragma unroll
    for (int c = 0; c < 4; ++c) {
        const int row = wk * 32 + l31;               // kv row (wave's half)
        koff[c] = row * 64 + (((2 * c + h) ^ (row & 7)) * 8);
    }
#pragma unroll
    for (int a = 0; a < 2; ++a)
#pragma unroll
        for (int ck = 0; ck < 2; ++ck) {
            const int row = a * 32 + l31;            // dh row
            const int ch  = 4 * wk + 2 * ck + h;     // kv chunk within row
            voff[a][ck] = row * 64 + ((ch ^ (row & 7)) * 8);
        }

    bf16x8 onef;
#pragma unroll
    for (int i = 0; i < 8; ++i) onef[i] = (bf16_t)1.0f;

    f32x16 acc_o[2][2];            // [qh][a]  D[m=q][n=dh]
    f32x16 acc_s[2];               // [qh]     rowsum (ones-column PV)
#pragma unroll
    for (int qh = 0; qh < 2; ++qh) {
#pragma unroll
        for (int i = 0; i < 16; ++i) {
            acc_o[qh][0][i] = 0.f; acc_o[qh][1][i] = 0.f; acc_s[qh][i] = 0.f;
        }
    }

    // stage one 128-kv iteration (both 64-subs) into buffer buf
    auto STAGE = [&](int t, int buf) {
        bf16_t* B = lKV + buf * 16384;
#pragma unroll
        for (int u = 0; u < 2; ++u) {
            const size_t kv0 = (size_t)(t * 128 + u * 64);
            async_ld16(gK0 + kv0 * D_MODEL, &B[u * 4096 + c0 * 8]);
            async_ld16(gK1 + kv0 * D_MODEL, &B[u * 4096 + c1 * 8]);
            async_ld16(gV0 + kv0, &B[8192 + u * 4096 + c0 * 8]);
            async_ld16(gV1 + kv0, &B[8192 + u * 4096 + c1 * 8]);
        }
    };

    // ---- prologue: stage iter 0 into buf 0, drain, barrier
    STAGE(0, 0);
    asm volatile("s_waitcnt vmcnt(0)\n\ts_barrier" ::: "memory");

    int cur = 0;
    const int NT2 = SEQ / 128;     // 16
    for (int t = 0; t < NT2; ++t) {
        // ---- issue next-iter DMA (8/thread); lands during this iter's math
        if (t + 1 < NT2) STAGE(t + 1, cur ^ 1);
        const bf16_t* Bc = lKV + cur * 16384;
        const bf16_t* lK0 = Bc;               // K sub 0
        const bf16_t* lK1 = Bc + 4096;        // K sub 1
        const bf16_t* lV0 = Bc + 8192;        // V sub 0
        const bf16_t* lV1 = Bc + 12288;       // V sub 1

        // ---- K frags, both subs
        bf16x8 kf0[4], kf1[4];
#pragma unroll
        for (int c = 0; c < 4; ++c) kf0[c] = *(const bf16x8*)&lK0[koff[c]];
#pragma unroll
        for (int c = 0; c < 4; ++c) kf1[c] = *(const bf16x8*)&lK1[koff[c]];

        // ---- QK both subs (independent chains; exp(u0) can issue under QK(u1))
        f32x16 st0[2], st1[2];
#pragma unroll
        for (int qh = 0; qh < 2; ++qh)
#pragma unroll
            for (int i = 0; i < 16; ++i) { st0[qh][i] = 0.f; st1[qh][i] = 0.f; }
        __builtin_amdgcn_s_setprio(1);
#pragma unroll
        for (int qh = 0; qh < 2; ++qh)
#pragma unroll
            for (int c = 0; c < 4; ++c)
                st0[qh] = __builtin_amdgcn_mfma_f32_32x32x16_bf16(
                    kf0[c], qf[qh][c], st0[qh], 0, 0, 0);
#pragma unroll
        for (int qh = 0; qh < 2; ++qh)
#pragma unroll
            for (int c = 0; c < 4; ++c)
                st1[qh] = __builtin_amdgcn_mfma_f32_32x32x16_bf16(
                    kf1[c], qf[qh][c], st1[qh], 0, 0, 0);
        __builtin_amdgcn_s_setprio(0);

        // ---- sub 0: exp2 + pack + permlane assemble + PV
        bf16x8 pf0[2][2];
#pragma unroll
        for (int qh = 0; qh < 2; ++qh) {
            bf16x4 pk[4];
#pragma unroll
            for (int g = 0; g < 4; ++g)
#pragma unroll
                for (int r = 0; r < 4; ++r)
                    pk[g][r] = (bf16_t)__builtin_amdgcn_exp2f(st0[qh][g * 4 + r]);
#pragma unroll
            for (int ck = 0; ck < 2; ++ck) {
                union { bf16x4 v; uint32_t d[2]; } ua, ub;
                ua.v = pk[2 * ck]; ub.v = pk[2 * ck + 1];
                uint32_t a0 = ua.d[0], b0 = ub.d[0];
                uint32_t a1 = ua.d[1], b1 = ub.d[1];
                plswap(a0, b0);
                plswap(a1, b1);
                union { bf16x8 v; uint32_t d[4]; } up;
                up.d[0] = a0; up.d[1] = a1; up.d[2] = b0; up.d[3] = b1;
                pf0[qh][ck] = up.v;
            }
        }
        __builtin_amdgcn_s_setprio(1);
#pragma unroll
        for (int qh = 0; qh < 2; ++qh)
#pragma unroll
            for (int ck = 0; ck < 2; ++ck)
                acc_s[qh] = __builtin_amdgcn_mfma_f32_32x32x16_bf16(
                    pf0[qh][ck], onef, acc_s[qh], 0, 0, 0);
#pragma unroll
        for (int a = 0; a < 2; ++a)
#pragma unroll
            for (int ck = 0; ck < 2; ++ck) {
                bf16x8 vf = *(const bf16x8*)&lV0[voff[a][ck]];
#pragma unroll
                for (int qh = 0; qh < 2; ++qh)
                    acc_o[qh][a] = __builtin_amdgcn_mfma_f32_32x32x16_bf16(
                        pf0[qh][ck], vf, acc_o[qh][a], 0, 0, 0);
            }
        __builtin_amdgcn_s_setprio(0);

        // ---- sub 1: exp2 + pack (issues under sub-0 PV) + PV
        bf16x8 pf1[2][2];
#pragma unroll
        for (int qh = 0; qh < 2; ++qh) {
            bf16x4 pk[4];
#pragma unroll
            for (int g = 0; g < 4; ++g)
#pragma unroll
                for (int r = 0; r < 4; ++r)
                    pk[g][r] = (bf16_t)__builtin_amdgcn_exp2f(st1[qh][g * 4 + r]);
#pragma unroll
            for (int ck = 0; ck < 2; ++ck) {
                union { bf16x4 v; uint32_t d[2]; } ua, ub;
                ua.v = pk[2 * ck]; ub.v = pk[2 * ck + 1];
                uint32_t a0 = ua.d[0], b0 = ub.d[0];
                uint32_t a1 = ua.d[1], b1 = ub.d[1];
                plswap(a0, b0);
                plswap(a1, b1);
                union { bf16x8 v; uint32_t d[4]; } up;
                up.d[0] = a0; up.d[1] = a1; up.d[2] = b0; up.d[3] = b1;
                pf1[qh][ck] = up.v;
            }
        }
        __builtin_amdgcn_s_setprio(1);
#pragma unroll
        for (int qh = 0; qh < 2; ++qh)
#pragma unroll
            for (int ck = 0; ck < 2; ++ck)
                acc_s[qh] = __builtin_amdgcn_mfma_f32_32x32x16_bf16(
                    pf1[qh][ck], onef, acc_s[qh], 0, 0, 0);
#pragma unroll
        for (int a = 0; a < 2; ++a)
#pragma unroll
            for (int ck = 0; ck < 2; ++ck) {
                bf16x8 vf = *(const bf16x8*)&lV1[voff[a][ck]];
#pragma unroll
                for (int qh = 0; qh < 2; ++qh)
                    acc_o[qh][a] = __builtin_amdgcn_mfma_f32_32x32x16_bf16(
                        pf1[qh][ck], vf, acc_o[qh][a], 0, 0, 0);
            }
        __builtin_amdgcn_s_setprio(0);

        // ---- own DMA + LDS ops drained, then block rendezvous (one asm so
        // nothing is scheduled between the waits and the barrier).
        asm volatile("s_waitcnt vmcnt(0) lgkmcnt(0)\n\ts_barrier" ::: "memory");
        cur ^= 1;
    }

    // ---- epilogue: combine wk pairs through LDS (arena reused; loop's final
    // barrier guarantees all tile reads are done).
    union F16 { f32x16 v; f32x4 q[4]; };
    float* blob = (float*)arena + ((size_t)(wq * 64 + lane)) * 100;  // 400B stride

    if (wk) {
#pragma unroll
        for (int qh = 0; qh < 2; ++qh) {
#pragma unroll
            for (int a = 0; a < 2; ++a) {
                F16 u; u.v = acc_o[qh][a];
#pragma unroll
                for (int i = 0; i < 4; ++i)
                    *(f32x4*)&blob[(qh * 8 + a * 4 + i) * 4] = u.q[i];
            }
            F16 s; s.v = acc_s[qh];
#pragma unroll
            for (int i = 0; i < 4; ++i)
                *(f32x4*)&blob[64 + (qh * 4 + i) * 4] = s.q[i];
        }
    }
    __syncthreads();
    if (!wk) {
#pragma unroll
        for (int qh = 0; qh < 2; ++qh) {
#pragma unroll
            for (int a = 0; a < 2; ++a) {
                F16 u; u.v = acc_o[qh][a];
#pragma unroll
                for (int i = 0; i < 4; ++i)
                    u.q[i] += *(const f32x4*)&blob[(qh * 8 + a * 4 + i) * 4];
                acc_o[qh][a] = u.v;
            }
            F16 s; s.v = acc_s[qh];
#pragma unroll
            for (int i = 0; i < 4; ++i)
                s.q[i] += *(const f32x4*)&blob[64 + (qh * 4 + i) * 4];
            acc_s[qh] = s.v;
        }

        // O / rowsum; 32x32 C-layout row = r + 8g + 4h, col = l31
#pragma unroll
        for (int qh = 0; qh < 2; ++qh)
#pragma unroll
            for (int g = 0; g < 4; ++g)
#pragma unroll
                for (int r = 0; r < 4; ++r) {
                    const float inv = 1.0f / acc_s[qh][g * 4 + r];
                    const int row = b_ * SEQ + q0 + wq * 64 + qh * 32 + (r + 8 * g + 4 * h);
                    const size_t rb = (size_t)row * D_MODEL + hh * DHEAD + l31;
                    Ob[rb]      = (bf16_t)(acc_o[qh][0][g * 4 + r] * inv);
                    Ob[rb + 32] = (bf16_t)(acc_o[qh][1][g * 4 + r] * inv);
                }
    }
}

// ---------------------------------------------------------------------------
extern "C" void kernel_launch(void* const* d_in, const int* in_sizes, int n_in,
                              void* d_out, int out_size, void* d_ws, size_t ws_size,
                              hipStream_t stream)
{
    const float* x  = (const float*)d_in[0];
    const float* Wq = (const float*)d_in[1];
    const float* Wk = (const float*)d_in[2];
    const float* Wv = (const float*)d_in[3];
    const float* Wo = (const float*)d_in[4];
    float* out = (float*)d_out;

    const size_t wmat = (size_t)D_MODEL * D_MODEL;  // 1M elements
    const size_t mat  = (size_t)NROWS * D_MODEL;    // 4M elements
    bf16_t* Wqb = (bf16_t*)d_ws;
    bf16_t* Wkb = Wqb + wmat;
    bf16_t* Wvb = Wkb + wmat;
    bf16_t* Wob = Wvb + wmat;
    bf16_t* Xb  = Wob + wmat;
    bf16_t* Qb  = Xb + mat;
    bf16_t* Kb  = Qb + mat;
    bf16_t* Vt  = Kb + mat;                          // [bh][dh][s]
    bf16_t* Ab  = Qb;                                // alias (see k_attn)

    dim3 blk(256);
    k_cvt<<<dim3(4096), blk, 0, stream>>>(Wq, Wk, Wv, Wo, x, Wqb, Wkb, Wvb, Wob, Xb);
    k_gemm_qkv<<<dim3(32, 24), blk, 0, stream>>>(Xb, Wqb, Wkb, Wvb, Qb, Kb, Vt);
    k_attn<<<dim3(32, 16), blk, 0, stream>>>(Qb, Kb, Vt, Ab);
    k_gemm_out<<<dim3(64, 8), blk, 0, stream>>>(Ab, Wob, out);
}

// Round 9
// 179.068 us; speedup vs baseline: 1.0354x; 1.0219x over previous
//
#include <hip/hip_runtime.h>
#include <stdint.h>

typedef __bf16 bf16_t;
typedef __bf16 bf16x4 __attribute__((ext_vector_type(4)));
typedef __bf16 bf16x8 __attribute__((ext_vector_type(8)));
typedef float  f32x4  __attribute__((ext_vector_type(4)));
typedef float  f32x16 __attribute__((ext_vector_type(16)));

#define D_MODEL 1024
#define SEQ     2048
#define BATCH   2
#define NHEAD   16
#define DHEAD   64
#define NROWS   (BATCH*SEQ)   // 4096
#define LDT     72            // GEMM V-transpose buffer stride (16B-aligned)

// log2(e): folded into Q scale so attn uses v_exp_f32 (exp2) directly.
#define QSCALE  (0.125f * 1.4426950408889634f)

// async 16B global->LDS DMA (m97). LDS dest must be wave-uniform base + lane*16.
__device__ __forceinline__ void async_ld16(const bf16_t* g, bf16_t* l) {
    __builtin_amdgcn_global_load_lds(
        (const __attribute__((address_space(1))) uint32_t*)(uintptr_t)g,
        (__attribute__((address_space(3))) uint32_t*)(uintptr_t)l,
        16, 0, 0);
}

__device__ __forceinline__ bf16x8 cvt8(f32x4 lo, f32x4 hi) {
    bf16x8 o;
#pragma unroll
    for (int i = 0; i < 4; ++i) { o[i] = (bf16_t)lo[i]; o[4 + i] = (bf16_t)hi[i]; }
    return o;
}

// v_permlane32_swap_b32 a, b:  a' = {a[0:31], b[0:31]},  b' = {a[32:63], b[32:63]}
__device__ __forceinline__ void plswap(uint32_t& a, uint32_t& b) {
    asm("v_permlane32_swap_b32 %0, %1" : "+v"(a), "+v"(b));
}

// ---------------------------------------------------------------------------
// f32 -> bf16 pre-convert of Wq,Wk,Wv,Wo (512 blocks each) + x (2048 blocks).
// ---------------------------------------------------------------------------
__global__ void __launch_bounds__(256)
k_cvt(const float* __restrict__ w0, const float* __restrict__ w1,
      const float* __restrict__ w2, const float* __restrict__ w3,
      const float* __restrict__ x,
      bf16_t* __restrict__ o0, bf16_t* __restrict__ o1,
      bf16_t* __restrict__ o2, bf16_t* __restrict__ o3,
      bf16_t* __restrict__ ox)
{
    const int blk = blockIdx.x;
    const float* s; bf16_t* d; int bi;
    if (blk < 2048) { s = x; d = ox; bi = blk; }
    else {
        const int t = blk - 2048, sel = t >> 9; bi = t & 511;
        s = (sel == 0) ? w0 : (sel == 1) ? w1 : (sel == 2) ? w2 : w3;
        d = (sel == 0) ? o0 : (sel == 1) ? o1 : (sel == 2) ? o2 : o3;
    }
    const size_t i = ((size_t)bi * 256 + threadIdx.x) * 8;
    *(bf16x8*)(d + i) = cvt8(*(const f32x4*)(s + i), *(const f32x4*)(s + i + 4));
}

// ---------------------------------------------------------------------------
// MT x 128 GEMM tile: Y = X @ W^T * oscale. A and B bf16. MT in {64,128}.
// Staging: global_load_lds width=16, 32-elem LDS rows, XOR-4 chunk swizzle.
// DBUF=false: r5's serial loop (sync -> STAGE -> sync -> compute), known-good.
// DBUF=true : 2-phase stage-ahead built ONLY from __syncthreads() (no inline
//   asm). Invariant (compiler semantics): each __syncthreads() drains every
//   wave's DMA (vmcnt) and ds_reads (lgkmcnt) then barriers -> next iter reads
//   buf^1 fully staged, and overwrites buf with no pending readers.
// OUT_MODE: 0 = bf16 row-major; 1 = bf16 V^T [bh][dh][s] (MT=128 only);
//           2 = f32 row-major.
// ---------------------------------------------------------------------------
template <int OUT_MODE, int MT, bool DBUF>
__device__ __forceinline__ void gemmT(bf16_t* __restrict__ smem,
                                      const bf16_t* __restrict__ X,
                                      const bf16_t* __restrict__ W,
                                      void* __restrict__ Yv,
                                      int m0, int n0, float oscale)
{
    constexpr int FM  = MT / 32;           // A-frags (16-row) per wave
    constexpr int BUF = (MT + 128) * 32;   // elems per LDS buffer

    const int tid  = threadIdx.x;
    const int lane = tid & 63;
    const int w    = tid >> 6;
    const int l15  = lane & 15;
    const int quad = lane >> 4;

    // B staging: 512 chunks, 2 per thread
    const int cB0 = tid, cB1 = tid + 256;
    const int rB0 = cB0 >> 2, rB1 = cB1 >> 2;
    const int kB0 = (cB0 & 3) ^ ((rB0 >> 1) & 3);
    const int kB1 = (cB1 & 3) ^ ((rB1 >> 1) & 3);
    const bf16_t* gB0 = W + (size_t)(n0 + rB0) * D_MODEL + kB0 * 8;
    const bf16_t* gB1 = W + (size_t)(n0 + rB1) * D_MODEL + kB1 * 8;

    // A staging: MT*4 chunks (MT=128: 2/thread, MT=64: 1/thread)
    const int cA0 = tid;
    const int rA0 = cA0 >> 2;
    const int kA0 = (cA0 & 3) ^ ((rA0 >> 1) & 3);
    const bf16_t* gA0 = X + (size_t)(m0 + rA0) * D_MODEL + kA0 * 8;
    const int cA1 = tid + 256;
    const int rA1 = cA1 >> 2;
    const int kA1 = (cA1 & 3) ^ ((rA1 >> 1) & 3);
    const bf16_t* gA1 = X + (size_t)(m0 + rA1) * D_MODEL + kA1 * 8;

    int am[FM], bn[4];
    const int mw = (w >> 1) * (MT / 2), nw = (w & 1) * 64;
#pragma unroll
    for (int i = 0; i < FM; ++i) {
        const int ra = mw + i * 16 + l15;
        am[i] = ra * 32 + (quad ^ ((ra >> 1) & 3)) * 8;
    }
#pragma unroll
    for (int i = 0; i < 4; ++i) {
        const int rb = nw + i * 16 + l15;
        bn[i] = rb * 32 + (quad ^ ((rb >> 1) & 3)) * 8;
    }

    f32x4 acc[FM][4];
#pragma unroll
    for (int i = 0; i < FM; ++i)
#pragma unroll
        for (int j = 0; j < 4; ++j) acc[i][j] = f32x4{0.f, 0.f, 0.f, 0.f};

    auto STAGE = [&](int k0, int b) {
        bf16_t* lA = smem + b * BUF;
        bf16_t* lB = lA + MT * 32;
        async_ld16(gA0 + k0, &lA[cA0 * 8]);
        if constexpr (MT == 128) async_ld16(gA1 + k0, &lA[cA1 * 8]);
        async_ld16(gB0 + k0, &lB[cB0 * 8]);
        async_ld16(gB1 + k0, &lB[cB1 * 8]);
    };
    auto COMPUTE = [&](int b) {
        const bf16_t* lA = smem + b * BUF;
        const bf16_t* lB = lA + MT * 32;
        bf16x8 af[FM], bfr[4];
#pragma unroll
        for (int i = 0; i < FM; ++i) af[i] = *(const bf16x8*)&lA[am[i]];
#pragma unroll
        for (int i = 0; i < 4; ++i) bfr[i] = *(const bf16x8*)&lB[bn[i]];
#pragma unroll
        for (int mi = 0; mi < FM; ++mi)
#pragma unroll
            for (int ni = 0; ni < 4; ++ni)
                acc[mi][ni] = __builtin_amdgcn_mfma_f32_16x16x32_bf16(
                    af[mi], bfr[ni], acc[mi][ni], 0, 0, 0);
    };

    if constexpr (DBUF) {
        STAGE(0, 0);
        __syncthreads();
        int buf = 0;
        for (int k0 = 0; k0 < D_MODEL; k0 += 32) {
            if (k0 + 32 < D_MODEL) STAGE(k0 + 32, buf ^ 1);
            COMPUTE(buf);
            __syncthreads();
            buf ^= 1;
        }
    } else {
        for (int k0 = 0; k0 < D_MODEL; k0 += 32) {
            __syncthreads();
            STAGE(k0, 0);
            __syncthreads();
            COMPUTE(0);
        }
    }

    if constexpr (OUT_MODE == 1) {
        bf16_t* lT = smem;                        // 128 cols x LDT (reuse)
#pragma unroll
        for (int h0 = 0; h0 < 2; ++h0) {
            __syncthreads();
            if ((w >> 1) == h0) {
#pragma unroll
                for (int mi = 0; mi < FM; ++mi)
#pragma unroll
                    for (int ni = 0; ni < 4; ++ni) {
                        bf16x4 pk;
#pragma unroll
                        for (int r = 0; r < 4; ++r)
                            pk[r] = (bf16_t)(acc[mi][ni][r] * oscale);
                        const int col = nw + ni * 16 + l15;
                        *(bf16x4*)&lT[col * LDT + mi * 16 + quad * 4] = pk;
                    }
            }
            __syncthreads();
            const int col = tid & 127;
            const int seg = tid >> 7;
            const int brow = m0 + h0 * 64;
            const int b = brow >> 11, sb = brow & 2047;
            const int cg = n0 + col;              // h*64+dh
            bf16_t* dst = (bf16_t*)Yv +
                ((size_t)((b << 4) | (cg >> 6)) * 64 + (cg & 63)) * SEQ + sb;
#pragma unroll
            for (int u = 0; u < 4; ++u)
                *(bf16x8*)(dst + seg * 32 + u * 8) =
                    *(const bf16x8*)&lT[col * LDT + seg * 32 + u * 8];
        }
    } else {
        // C/D layout col = lane&15, row = quad*4 + reg (m89-verified)
#pragma unroll
        for (int mi = 0; mi < FM; ++mi)
#pragma unroll
            for (int ni = 0; ni < 4; ++ni)
#pragma unroll
                for (int r = 0; r < 4; ++r) {
                    const int row = m0 + mw + mi * 16 + quad * 4 + r;
                    const int col = n0 + nw + ni * 16 + l15;
                    const float vv = acc[mi][ni][r] * oscale;
                    if constexpr (OUT_MODE == 0)
                        ((bf16_t*)Yv)[(size_t)row * D_MODEL + col] = (bf16_t)vv;
                    else
                        ((float*)Yv)[(size_t)row * D_MODEL + col] = vv;
                }
    }
}

// 768 blocks. XCD swizzle (id%8 = hw XCD): XCD k processes y' in {3k..3k+2}
// -> 3 W-panels (768KB) L2-resident per XCD. DBUF=true (stage-ahead via
// __syncthreads only — no inline asm; the r7 asm variant raced).
__global__ void __launch_bounds__(256, 3)
k_gemm_qkv(const bf16_t* __restrict__ X,
           const bf16_t* __restrict__ Wq, const bf16_t* __restrict__ Wk,
           const bf16_t* __restrict__ Wv,
           bf16_t* __restrict__ Qb, bf16_t* __restrict__ Kb, bf16_t* __restrict__ Vt)
{
    __shared__ __align__(16) bf16_t smem[16384];       // 32 KiB: 2 x (128+128)x32
    const int id = blockIdx.x + 32 * blockIdx.y;       // 0..767
    const int s  = (id & 7) * 96 + (id >> 3);          // bijective (768%8==0)
    const int m0 = (s & 31) * 128;
    const int yp = s >> 5;                             // 0..23
    const int sel = yp >> 3;                           // 0=Q 1=K 2=V
    const int n0  = (yp & 7) * 128;
    if (sel == 0)      gemmT<0,128,true>(smem, X, Wq, Qb, m0, n0, QSCALE);
    else if (sel == 1) gemmT<0,128,true>(smem, X, Wk, Kb, m0, n0, 1.0f);
    else               gemmT<1,128,true>(smem, X, Wv, Vt, m0, n0, 1.0f);
}

// MT=64 tiles -> 512 blocks = 2 blocks/CU. XCD swizzle: XCD k gets n-tile k.
// Serial loop (DBUF=false) — exact r5 code path (known-good).
__global__ void __launch_bounds__(256, 2)
k_gemm_out(const bf16_t* __restrict__ X, const bf16_t* __restrict__ W,
           float* __restrict__ Y)
{
    __shared__ __align__(16) bf16_t smem[64 * 32 + 128 * 32];  // 12 KiB
    const int id = blockIdx.x + 64 * blockIdx.y;       // 0..511
    const int s  = (id & 7) * 64 + (id >> 3);          // bijective (512%8==0)
    const int m0 = (s & 63) * 64;
    const int n0 = (s >> 6) * 128;
    gemmT<2,64,false>(smem, X, W, Y, m0, n0, 1.0f);
}

// ---------------------------------------------------------------------------
// Attention — byte-exact restore of the round-2 kernel (best measured:
// 48.6 us, passed 3x). Q-tile 128, 4 waves 2x2: wq = 64-row q-strip, wk =
// 32-row kv-half. Per wave-iter: 4 K + 4 V ds_read_b128 (each serving 2 qh),
// 20 MFMA, 32 exp2. Partner h-exchange via v_permlane32_swap_b32. Row-sum
// via ones-column MFMA (acc_s layout == acc_o). Double-buffered K/V; stage
// t+1 issued before compute of t; ONE fused vmcnt/lgkmcnt + barrier per tile.
// Epilogue combines wk pairs once through the reused LDS arena.
// Ob may alias Qb (Q read to regs up-front; block-disjoint slices).
// ---------------------------------------------------------------------------
__global__ void __launch_bounds__(256, 2)
k_attn(const bf16_t* __restrict__ Qb, const bf16_t* __restrict__ Kb,
       const bf16_t* __restrict__ Vt, bf16_t* __restrict__ Ob)
{
    // arena: main loop lK[2][4096]+lV[2][4096] bf16 (32 KiB);
    // epilogue reuses it as 2 x 64 blobs of 96 floats (stride 100 -> 50 KiB).
    __shared__ __align__(16) char arena[51200];
    bf16_t* lK = (bf16_t*)arena;               // [2][64*64] swizzled chunks
    bf16_t* lV = (bf16_t*)(arena + 16384);     // [2][64*64] swizzled chunks

    const int tid  = threadIdx.x;
    const int lane = tid & 63;
    const int w    = tid >> 6;
    const int wq   = w >> 1;      // q-strip (64 rows)
    const int wk   = w & 1;       // kv-half (32 rows)
    const int l31  = lane & 31;
    const int h    = lane >> 5;

    const int bh = blockIdx.x;    // 0..31
    const int b_ = bh >> 4, hh = bh & 15;
    const int q0 = blockIdx.y * 128;

    const size_t base = (size_t)b_ * SEQ * D_MODEL + (size_t)hh * DHEAD;
    const bf16_t* Qp = Qb + base;
    const bf16_t* Kp = Kb + base;
    const bf16_t* Vp = Vt + (size_t)bh * DHEAD * SEQ;   // [dh][s]

    // Q B-frags in regs: B[n = q = l31][k = dh-local h*8+j], chunk c = dh/16
    bf16x8 qf[2][4];
#pragma unroll
    for (int qh = 0; qh < 2; ++qh) {
        const int qrow = q0 + wq * 64 + qh * 32 + l31;
#pragma unroll
        for (int c = 0; c < 4; ++c)
            qf[qh][c] = *(const bf16x8*)&Qp[(size_t)qrow * D_MODEL + c * 16 + h * 8];
    }

    // staging: 512 chunks per tile, 2 per thread; chunk c -> row c>>3, slot
    // c&7, global chunk g = (c&7) ^ (row&7). Note (r0+32)&7 == r0&7.
    const int c0 = tid, c1 = tid + 256;
    const int r0 = c0 >> 3, g0 = (c0 & 7) ^ (r0 & 7);
    const int r1 = r0 + 32;
    const bf16_t* gK0 = Kp + (size_t)r0 * D_MODEL + g0 * 8;
    const bf16_t* gK1 = Kp + (size_t)r1 * D_MODEL + g0 * 8;
    const bf16_t* gV0 = Vp + (size_t)r0 * SEQ + g0 * 8;
    const bf16_t* gV1 = Vp + (size_t)r1 * SEQ + g0 * 8;

    // fragment read offsets (row-dependent XOR slot)
    int koff[4], voff[2][2];
#pragma unroll
    for (int c = 0; c < 4; ++c) {
        const int row = wk * 32 + l31;               // kv row (wave's half)
        koff[c] = row * 64 + (((2 * c + h) ^ (row & 7)) * 8);
    }
#pragma unroll
    for (int a = 0; a < 2; ++a)
#pragma unroll
        for (int ck = 0; ck < 2; ++ck) {
            const int row = a * 32 + l31;            // dh row
            const int ch  = 4 * wk + 2 * ck + h;     // kv chunk within row
            voff[a][ck] = row * 64 + ((ch ^ (row & 7)) * 8);
        }

    bf16x8 onef;
#pragma unroll
    for (int i = 0; i < 8; ++i) onef[i] = (bf16_t)1.0f;

    f32x16 acc_o[2][2];            // [qh][a]  D[m=q][n=dh]
    f32x16 acc_s[2];               // [qh]     rowsum (ones-column PV)
#pragma unroll
    for (int qh = 0; qh < 2; ++qh) {
#pragma unroll
        for (int i = 0; i < 16; ++i) {
            acc_o[qh][0][i] = 0.f; acc_o[qh][1][i] = 0.f; acc_s[qh][i] = 0.f;
        }
    }

    // ---- prologue: stage tile 0 into buf 0, drain, barrier
    async_ld16(gK0, &lK[c0 * 8]);
    async_ld16(gK1, &lK[c1 * 8]);
    async_ld16(gV0, &lV[c0 * 8]);
    async_ld16(gV1, &lV[c1 * 8]);
    asm volatile("s_waitcnt vmcnt(0)\n\ts_barrier" ::: "memory");

    int cur = 0;
    const int NT = SEQ / 64;       // 32
    for (int t = 0; t < NT; ++t) {
        // ---- issue next-tile DMA first; latency hides under this tile's math
        if (t + 1 < NT) {
            const int kv0 = (t + 1) * 64;
            const int nb = (cur ^ 1) * 4096;
            async_ld16(gK0 + (size_t)kv0 * D_MODEL, &lK[nb + c0 * 8]);
            async_ld16(gK1 + (size_t)kv0 * D_MODEL, &lK[nb + c1 * 8]);
            async_ld16(gV0 + kv0, &lV[nb + c0 * 8]);
            async_ld16(gV1 + kv0, &lV[nb + c1 * 8]);
        }
        const bf16_t* lKc = lK + cur * 4096;
        const bf16_t* lVc = lV + cur * 4096;

        // ---- S^T: D[m = kv-local(32)][n = q(32)], shared kf across both qh
        bf16x8 kf[4];
#pragma unroll
        for (int c = 0; c < 4; ++c) kf[c] = *(const bf16x8*)&lKc[koff[c]];

        f32x16 st[2];
#pragma unroll
        for (int qh = 0; qh < 2; ++qh)
#pragma unroll
            for (int i = 0; i < 16; ++i) st[qh][i] = 0.f;
        __builtin_amdgcn_s_setprio(1);
#pragma unroll
        for (int qh = 0; qh < 2; ++qh)
#pragma unroll
            for (int c = 0; c < 4; ++c)
                st[qh] = __builtin_amdgcn_mfma_f32_32x32x16_bf16(
                    kf[c], qf[qh][c], st[qh], 0, 0, 0);
        __builtin_amdgcn_s_setprio(0);

        // ---- exp2 + pack: pk[qh][g][r] = P[kv-local = 8g+4h+r][q = l31]
        bf16x4 pk[2][4];
#pragma unroll
        for (int qh = 0; qh < 2; ++qh)
#pragma unroll
            for (int g = 0; g < 4; ++g)
#pragma unroll
                for (int r = 0; r < 4; ++r)
                    pk[qh][g][r] = (bf16_t)__builtin_amdgcn_exp2f(st[qh][g * 4 + r]);

        // ---- assemble PV A-frags via permlane32_swap:
        // pf[qh][ck] = A[m = q = l31][k = kv-local 16ck + 8h + j]
        bf16x8 pf[2][2];
#pragma unroll
        for (int qh = 0; qh < 2; ++qh)
#pragma unroll
            for (int ck = 0; ck < 2; ++ck) {
                union { bf16x4 v; uint32_t d[2]; } ua, ub;
                ua.v = pk[qh][2 * ck];
                ub.v = pk[qh][2 * ck + 1];
                uint32_t a0 = ua.d[0], b0 = ub.d[0];
                uint32_t a1 = ua.d[1], b1 = ub.d[1];
                plswap(a0, b0);
                plswap(a1, b1);
                union { bf16x8 v; uint32_t d[4]; } up;
                up.d[0] = a0; up.d[1] = a1; up.d[2] = b0; up.d[3] = b1;
                pf[qh][ck] = up.v;
            }

        // ---- PV + ones-column row-sum
        __builtin_amdgcn_s_setprio(1);
#pragma unroll
        for (int qh = 0; qh < 2; ++qh)
#pragma unroll
            for (int ck = 0; ck < 2; ++ck)
                acc_s[qh] = __builtin_amdgcn_mfma_f32_32x32x16_bf16(
                    pf[qh][ck], onef, acc_s[qh], 0, 0, 0);
#pragma unroll
        for (int a = 0; a < 2; ++a)
#pragma unroll
            for (int ck = 0; ck < 2; ++ck) {
                bf16x8 vf = *(const bf16x8*)&lVc[voff[a][ck]];
#pragma unroll
                for (int qh = 0; qh < 2; ++qh)
                    acc_o[qh][a] = __builtin_amdgcn_mfma_f32_32x32x16_bf16(
                        pf[qh][ck], vf, acc_o[qh][a], 0, 0, 0);
            }
        __builtin_amdgcn_s_setprio(0);

        // ---- own DMA + LDS ops drained, then block rendezvous (one asm so
        // nothing is scheduled between the waits and the barrier).
        asm volatile("s_waitcnt vmcnt(0) lgkmcnt(0)\n\ts_barrier" ::: "memory");
        cur ^= 1;
    }

    // ---- epilogue: combine wk pairs through LDS (arena reused; loop's final
    // barrier guarantees all tile reads are done).
    union F16 { f32x16 v; f32x4 q[4]; };
    float* blob = (float*)arena + ((size_t)(wq * 64 + lane)) * 100;  // 400B stride

    if (wk) {
#pragma unroll
        for (int qh = 0; qh < 2; ++qh) {
#pragma unroll
            for (int a = 0; a < 2; ++a) {
                F16 u; u.v = acc_o[qh][a];
#pragma unroll
                for (int i = 0; i < 4; ++i)
                    *(f32x4*)&blob[(qh * 8 + a * 4 + i) * 4] = u.q[i];
            }
            F16 s; s.v = acc_s[qh];
#pragma unroll
            for (int i = 0; i < 4; ++i)
                *(f32x4*)&blob[64 + (qh * 4 + i) * 4] = s.q[i];
        }
    }
    __syncthreads();
    if (!wk) {
#pragma unroll
        for (int qh = 0; qh < 2; ++qh) {
#pragma unroll
            for (int a = 0; a < 2; ++a) {
                F16 u; u.v = acc_o[qh][a];
#pragma unroll
                for (int i = 0; i < 4; ++i)
                    u.q[i] += *(const f32x4*)&blob[(qh * 8 + a * 4 + i) * 4];
                acc_o[qh][a] = u.v;
            }
            F16 s; s.v = acc_s[qh];
#pragma unroll
            for (int i = 0; i < 4; ++i)
                s.q[i] += *(const f32x4*)&blob[64 + (qh * 4 + i) * 4];
            acc_s[qh] = s.v;
        }

        // O / rowsum; 32x32 C-layout row = r + 8g + 4h, col = l31
#pragma unroll
        for (int qh = 0; qh < 2; ++qh)
#pragma unroll
            for (int g = 0; g < 4; ++g)
#pragma unroll
                for (int r = 0; r < 4; ++r) {
                    const float inv = 1.0f / acc_s[qh][g * 4 + r];
                    const int row = b_ * SEQ + q0 + wq * 64 + qh * 32 + (r + 8 * g + 4 * h);
                    const size_t rb = (size_t)row * D_MODEL + hh * DHEAD + l31;
                    Ob[rb]      = (bf16_t)(acc_o[qh][0][g * 4 + r] * inv);
                    Ob[rb + 32] = (bf16_t)(acc_o[qh][1][g * 4 + r] * inv);
                }
    }
}

// ---------------------------------------------------------------------------
extern "C" void kernel_launch(void* const* d_in, const int* in_sizes, int n_in,
                              void* d_out, int out_size, void* d_ws, size_t ws_size,
                              hipStream_t stream)
{
    const float* x  = (const float*)d_in[0];
    const float* Wq = (const float*)d_in[1];
    const float* Wk = (const float*)d_in[2];
    const float* Wv = (const float*)d_in[3];
    const float* Wo = (const float*)d_in[4];
    float* out = (float*)d_out;

    const size_t wmat = (size_t)D_MODEL * D_MODEL;  // 1M elements
    const size_t mat  = (size_t)NROWS * D_MODEL;    // 4M elements
    bf16_t* Wqb = (bf16_t*)d_ws;
    bf16_t* Wkb = Wqb + wmat;
    bf16_t* Wvb = Wkb + wmat;
    bf16_t* Wob = Wvb + wmat;
    bf16_t* Xb  = Wob + wmat;
    bf16_t* Qb  = Xb + mat;
    bf16_t* Kb  = Qb + mat;
    bf16_t* Vt  = Kb + mat;                          // [bh][dh][s]
    bf16_t* Ab  = Qb;                                // alias (see k_attn)

    dim3 blk(256);
    k_cvt<<<dim3(4096), blk, 0, stream>>>(Wq, Wk, Wv, Wo, x, Wqb, Wkb, Wvb, Wob, Xb);
    k_gemm_qkv<<<dim3(32, 24), blk, 0, stream>>>(Xb, Wqb, Wkb, Wvb, Qb, Kb, Vt);
    k_attn<<<dim3(32, 16), blk, 0, stream>>>(Qb, Kb, Vt, Ab);
    k_gemm_out<<<dim3(64, 8), blk, 0, stream>>>(Ab, Wob, out);
}

// Round 10
// 178.222 us; speedup vs baseline: 1.0404x; 1.0047x over previous
//
#include <hip/hip_runtime.h>
#include <stdint.h>

typedef __bf16 bf16_t;
typedef __bf16 bf16x4 __attribute__((ext_vector_type(4)));
typedef __bf16 bf16x8 __attribute__((ext_vector_type(8)));
typedef float  f32x4  __attribute__((ext_vector_type(4)));
typedef float  f32x16 __attribute__((ext_vector_type(16)));

#define D_MODEL 1024
#define SEQ     2048
#define BATCH   2
#define NHEAD   16
#define DHEAD   64
#define NROWS   (BATCH*SEQ)   // 4096
#define LDT     72            // GEMM V-transpose buffer stride (16B-aligned)

// log2(e): folded into Q scale so attn uses v_exp_f32 (exp2) directly.
#define QSCALE  (0.125f * 1.4426950408889634f)

// async 16B global->LDS DMA (m97). LDS dest must be wave-uniform base + lane*16.
__device__ __forceinline__ void async_ld16(const bf16_t* g, bf16_t* l) {
    __builtin_amdgcn_global_load_lds(
        (const __attribute__((address_space(1))) uint32_t*)(uintptr_t)g,
        (__attribute__((address_space(3))) uint32_t*)(uintptr_t)l,
        16, 0, 0);
}

__device__ __forceinline__ bf16x8 cvt8(f32x4 lo, f32x4 hi) {
    bf16x8 o;
#pragma unroll
    for (int i = 0; i < 4; ++i) { o[i] = (bf16_t)lo[i]; o[4 + i] = (bf16_t)hi[i]; }
    return o;
}

// v_permlane32_swap_b32 a, b:  a'[l<32]=a[l], a'[l>=32]=b[l-32];
//                              b'[l<32]=a[l+32], b'[l>=32]=b[l]
__device__ __forceinline__ void plswap(uint32_t& a, uint32_t& b) {
    asm("v_permlane32_swap_b32 %0, %1" : "+v"(a), "+v"(b));
}

// ---------------------------------------------------------------------------
// f32 -> bf16 pre-convert of Wq,Wk,Wv,Wo (512 blocks each) + x (2048 blocks).
// ---------------------------------------------------------------------------
__global__ void __launch_bounds__(256)
k_cvt(const float* __restrict__ w0, const float* __restrict__ w1,
      const float* __restrict__ w2, const float* __restrict__ w3,
      const float* __restrict__ x,
      bf16_t* __restrict__ o0, bf16_t* __restrict__ o1,
      bf16_t* __restrict__ o2, bf16_t* __restrict__ o3,
      bf16_t* __restrict__ ox)
{
    const int blk = blockIdx.x;
    const float* s; bf16_t* d; int bi;
    if (blk < 2048) { s = x; d = ox; bi = blk; }
    else {
        const int t = blk - 2048, sel = t >> 9; bi = t & 511;
        s = (sel == 0) ? w0 : (sel == 1) ? w1 : (sel == 2) ? w2 : w3;
        d = (sel == 0) ? o0 : (sel == 1) ? o1 : (sel == 2) ? o2 : o3;
    }
    const size_t i = ((size_t)bi * 256 + threadIdx.x) * 8;
    *(bf16x8*)(d + i) = cvt8(*(const f32x4*)(s + i), *(const f32x4*)(s + i + 4));
}

// ---------------------------------------------------------------------------
// MT x 128 GEMM tile: Y = X @ W^T * oscale. A and B bf16. MT in {64,128}.
// Staging: global_load_lds width=16, 32-elem LDS rows, XOR-4 chunk swizzle.
// DBUF=false: serial loop (sync -> STAGE -> sync -> compute), known-good.
// DBUF=true : 2-phase stage-ahead via __syncthreads() only (measured null vs
//   serial at r9, kept: no inline asm, same perf, deeper pipeline latitude).
// OUT_MODE: 0 = bf16 row-major; 1 = bf16 V^T [bh][dh][s] (MT=128 only);
//           2 = f32 row-major.
// ---------------------------------------------------------------------------
template <int OUT_MODE, int MT, bool DBUF>
__device__ __forceinline__ void gemmT(bf16_t* __restrict__ smem,
                                      const bf16_t* __restrict__ X,
                                      const bf16_t* __restrict__ W,
                                      void* __restrict__ Yv,
                                      int m0, int n0, float oscale)
{
    constexpr int FM  = MT / 32;           // A-frags (16-row) per wave
    constexpr int BUF = (MT + 128) * 32;   // elems per LDS buffer

    const int tid  = threadIdx.x;
    const int lane = tid & 63;
    const int w    = tid >> 6;
    const int l15  = lane & 15;
    const int quad = lane >> 4;

    // B staging: 512 chunks, 2 per thread
    const int cB0 = tid, cB1 = tid + 256;
    const int rB0 = cB0 >> 2, rB1 = cB1 >> 2;
    const int kB0 = (cB0 & 3) ^ ((rB0 >> 1) & 3);
    const int kB1 = (cB1 & 3) ^ ((rB1 >> 1) & 3);
    const bf16_t* gB0 = W + (size_t)(n0 + rB0) * D_MODEL + kB0 * 8;
    const bf16_t* gB1 = W + (size_t)(n0 + rB1) * D_MODEL + kB1 * 8;

    // A staging: MT*4 chunks (MT=128: 2/thread, MT=64: 1/thread)
    const int cA0 = tid;
    const int rA0 = cA0 >> 2;
    const int kA0 = (cA0 & 3) ^ ((rA0 >> 1) & 3);
    const bf16_t* gA0 = X + (size_t)(m0 + rA0) * D_MODEL + kA0 * 8;
    const int cA1 = tid + 256;
    const int rA1 = cA1 >> 2;
    const int kA1 = (cA1 & 3) ^ ((rA1 >> 1) & 3);
    const bf16_t* gA1 = X + (size_t)(m0 + rA1) * D_MODEL + kA1 * 8;

    int am[FM], bn[4];
    const int mw = (w >> 1) * (MT / 2), nw = (w & 1) * 64;
#pragma unroll
    for (int i = 0; i < FM; ++i) {
        const int ra = mw + i * 16 + l15;
        am[i] = ra * 32 + (quad ^ ((ra >> 1) & 3)) * 8;
    }
#pragma unroll
    for (int i = 0; i < 4; ++i) {
        const int rb = nw + i * 16 + l15;
        bn[i] = rb * 32 + (quad ^ ((rb >> 1) & 3)) * 8;
    }

    f32x4 acc[FM][4];
#pragma unroll
    for (int i = 0; i < FM; ++i)
#pragma unroll
        for (int j = 0; j < 4; ++j) acc[i][j] = f32x4{0.f, 0.f, 0.f, 0.f};

    auto STAGE = [&](int k0, int b) {
        bf16_t* lA = smem + b * BUF;
        bf16_t* lB = lA + MT * 32;
        async_ld16(gA0 + k0, &lA[cA0 * 8]);
        if constexpr (MT == 128) async_ld16(gA1 + k0, &lA[cA1 * 8]);
        async_ld16(gB0 + k0, &lB[cB0 * 8]);
        async_ld16(gB1 + k0, &lB[cB1 * 8]);
    };
    auto COMPUTE = [&](int b) {
        const bf16_t* lA = smem + b * BUF;
        const bf16_t* lB = lA + MT * 32;
        bf16x8 af[FM], bfr[4];
#pragma unroll
        for (int i = 0; i < FM; ++i) af[i] = *(const bf16x8*)&lA[am[i]];
#pragma unroll
        for (int i = 0; i < 4; ++i) bfr[i] = *(const bf16x8*)&lB[bn[i]];
#pragma unroll
        for (int mi = 0; mi < FM; ++mi)
#pragma unroll
            for (int ni = 0; ni < 4; ++ni)
                acc[mi][ni] = __builtin_amdgcn_mfma_f32_16x16x32_bf16(
                    af[mi], bfr[ni], acc[mi][ni], 0, 0, 0);
    };

    if constexpr (DBUF) {
        STAGE(0, 0);
        __syncthreads();
        int buf = 0;
        for (int k0 = 0; k0 < D_MODEL; k0 += 32) {
            if (k0 + 32 < D_MODEL) STAGE(k0 + 32, buf ^ 1);
            COMPUTE(buf);
            __syncthreads();
            buf ^= 1;
        }
    } else {
        for (int k0 = 0; k0 < D_MODEL; k0 += 32) {
            __syncthreads();
            STAGE(k0, 0);
            __syncthreads();
            COMPUTE(0);
        }
    }

    if constexpr (OUT_MODE == 1) {
        bf16_t* lT = smem;                        // 128 cols x LDT (reuse)
#pragma unroll
        for (int h0 = 0; h0 < 2; ++h0) {
            __syncthreads();
            if ((w >> 1) == h0) {
#pragma unroll
                for (int mi = 0; mi < FM; ++mi)
#pragma unroll
                    for (int ni = 0; ni < 4; ++ni) {
                        bf16x4 pk;
#pragma unroll
                        for (int r = 0; r < 4; ++r)
                            pk[r] = (bf16_t)(acc[mi][ni][r] * oscale);
                        const int col = nw + ni * 16 + l15;
                        *(bf16x4*)&lT[col * LDT + mi * 16 + quad * 4] = pk;
                    }
            }
            __syncthreads();
            const int col = tid & 127;
            const int seg = tid >> 7;
            const int brow = m0 + h0 * 64;
            const int b = brow >> 11, sb = brow & 2047;
            const int cg = n0 + col;              // h*64+dh
            bf16_t* dst = (bf16_t*)Yv +
                ((size_t)((b << 4) | (cg >> 6)) * 64 + (cg & 63)) * SEQ + sb;
#pragma unroll
            for (int u = 0; u < 4; ++u)
                *(bf16x8*)(dst + seg * 32 + u * 8) =
                    *(const bf16x8*)&lT[col * LDT + seg * 32 + u * 8];
        }
    } else {
        // C/D layout col = lane&15, row = quad*4 + reg (m89-verified)
#pragma unroll
        for (int mi = 0; mi < FM; ++mi)
#pragma unroll
            for (int ni = 0; ni < 4; ++ni)
#pragma unroll
                for (int r = 0; r < 4; ++r) {
                    const int row = m0 + mw + mi * 16 + quad * 4 + r;
                    const int col = n0 + nw + ni * 16 + l15;
                    const float vv = acc[mi][ni][r] * oscale;
                    if constexpr (OUT_MODE == 0)
                        ((bf16_t*)Yv)[(size_t)row * D_MODEL + col] = (bf16_t)vv;
                    else
                        ((float*)Yv)[(size_t)row * D_MODEL + col] = vv;
                }
    }
}

// 768 blocks = 3/CU. Round-10: plain blockIdx mapping (XCD swizzle removed —
// W panels are L2/L3-fit; m160: swizzle costs ~2% on L3-fit data). DBUF kept
// (r9: measured null vs serial, no inline asm).
__global__ void __launch_bounds__(256, 3)
k_gemm_qkv(const bf16_t* __restrict__ X,
           const bf16_t* __restrict__ Wq, const bf16_t* __restrict__ Wk,
           const bf16_t* __restrict__ Wv,
           bf16_t* __restrict__ Qb, bf16_t* __restrict__ Kb, bf16_t* __restrict__ Vt)
{
    __shared__ __align__(16) bf16_t smem[16384];       // 32 KiB: 2 x (128+128)x32
    const int sel = blockIdx.y >> 3;           // 0=Q 1=K 2=V
    const int n0  = (blockIdx.y & 7) * 128;
    const int m0  = blockIdx.x * 128;
    if (sel == 0)      gemmT<0,128,true>(smem, X, Wq, Qb, m0, n0, QSCALE);
    else if (sel == 1) gemmT<0,128,true>(smem, X, Wk, Kb, m0, n0, 1.0f);
    else               gemmT<1,128,true>(smem, X, Wv, Vt, m0, n0, 1.0f);
}

// Round-10: revert to MT=128, grid (32,8), plain mapping (the r0-r4 config;
// the r5 MT=64 "occupancy fix" halved MFMA:DS density per block and doubled
// B-panel staging — never isolated, suspected ~4us regression).
__global__ void __launch_bounds__(256, 3)
k_gemm_out(const bf16_t* __restrict__ X, const bf16_t* __restrict__ W,
           float* __restrict__ Y)
{
    __shared__ __align__(16) bf16_t smem[(128 + 128) * 32];    // 16 KiB
    gemmT<2,128,false>(smem, X, W, Y, blockIdx.x * 128, blockIdx.y * 128, 1.0f);
}

// ---------------------------------------------------------------------------
// Attention, Q-tile 128, r2 structure. 4 waves 2x2: wq = 64-row q-strip,
// wk = 32-row kv-half. Per wave-iter: 4 K + 4 V ds_read_b128, 16 MFMA,
// 32 exp2. Double-buffered K/V; stage t+1 before compute of t; ONE fused
// vmcnt/lgkmcnt + barrier per tile.
// Round-10 change: row-sum moved from ones-column MFMA (4/qh/iter = 256
// MFMA-pipe cyc/wave-iter) to f32 VALU adds on the already-live exp2 outputs
// (~64 cyc). r2's pipe audit: MFMA 35 + VALU 34 + DS 28 ~= 100% of wall, so
// wall ~= sum of pipes and shrinking the biggest term wins. Frees acc_s +
// onef (~36 VGPR). Per-lane rsum is for q = l31; the epilogue aligns it to
// O's row indexing via one 128-float sbuf broadcast (same-address reads ->
// free LDS broadcast): h-combine (shfl_xor 32) -> wk-combine (blob) ->
// sbuf[q_local] write by wk=0/h=0 -> barrier -> broadcast read.
// Ob may alias Qb (Q read to regs up-front; block-disjoint slices).
// ---------------------------------------------------------------------------
__global__ void __launch_bounds__(256, 2)
k_attn(const bf16_t* __restrict__ Qb, const bf16_t* __restrict__ Kb,
       const bf16_t* __restrict__ Vt, bf16_t* __restrict__ Ob)
{
    // arena: main loop lK[2][4096]+lV[2][4096] bf16 (32 KiB); epilogue reuses
    // [0,34816) as 128 blobs of 66 floats (stride 68) and [34816,35328) as
    // the 128-float rowsum sbuf.
    __shared__ __align__(16) char arena[51200];
    bf16_t* lK = (bf16_t*)arena;               // [2][64*64] swizzled chunks
    bf16_t* lV = (bf16_t*)(arena + 16384);     // [2][64*64] swizzled chunks

    const int tid  = threadIdx.x;
    const int lane = tid & 63;
    const int w    = tid >> 6;
    const int wq   = w >> 1;      // q-strip (64 rows)
    const int wk   = w & 1;       // kv-half (32 rows)
    const int l31  = lane & 31;
    const int h    = lane >> 5;

    const int bh = blockIdx.x;    // 0..31
    const int b_ = bh >> 4, hh = bh & 15;
    const int q0 = blockIdx.y * 128;

    const size_t base = (size_t)b_ * SEQ * D_MODEL + (size_t)hh * DHEAD;
    const bf16_t* Qp = Qb + base;
    const bf16_t* Kp = Kb + base;
    const bf16_t* Vp = Vt + (size_t)bh * DHEAD * SEQ;   // [dh][s]

    // Q B-frags in regs: B[n = q = l31][k = dh-local h*8+j], chunk c = dh/16
    bf16x8 qf[2][4];
#pragma unroll
    for (int qh = 0; qh < 2; ++qh) {
        const int qrow = q0 + wq * 64 + qh * 32 + l31;
#pragma unroll
        for (int c = 0; c < 4; ++c)
            qf[qh][c] = *(const bf16x8*)&Qp[(size_t)qrow * D_MODEL + c * 16 + h * 8];
    }

    // staging: 512 chunks per tile, 2 per thread; chunk c -> row c>>3, slot
    // c&7, global chunk g = (c&7) ^ (row&7). Note (r0+32)&7 == r0&7.
    const int c0 = tid, c1 = tid + 256;
    const int r0 = c0 >> 3, g0 = (c0 & 7) ^ (r0 & 7);
    const int r1 = r0 + 32;
    const bf16_t* gK0 = Kp + (size_t)r0 * D_MODEL + g0 * 8;
    const bf16_t* gK1 = Kp + (size_t)r1 * D_MODEL + g0 * 8;
    const bf16_t* gV0 = Vp + (size_t)r0 * SEQ + g0 * 8;
    const bf16_t* gV1 = Vp + (size_t)r1 * SEQ + g0 * 8;

    // fragment read offsets (row-dependent XOR slot)
    int koff[4], voff[2][2];
#pragma unroll
    for (int c = 0; c < 4; ++c) {
        const int row = wk * 32 + l31;               // kv row (wave's half)
        koff[c] = row * 64 + (((2 * c + h) ^ (row & 7)) * 8);
    }
#pragma unroll
    for (int a = 0; a < 2; ++a)
#pragma unroll
        for (int ck = 0; ck < 2; ++ck) {
            const int row = a * 32 + l31;            // dh row
            const int ch  = 4 * wk + 2 * ck + h;     // kv chunk within row
            voff[a][ck] = row * 64 + ((ch ^ (row & 7)) * 8);
        }

    f32x16 acc_o[2][2];            // [qh][a]  D[m=q][n=dh]
    float rsumf[2] = {0.f, 0.f};   // [qh] rowsum for q = l31 (this wave's
                                   // (wk, h) quadrant of kv slots)
#pragma unroll
    for (int qh = 0; qh < 2; ++qh)
#pragma unroll
        for (int i = 0; i < 16; ++i) { acc_o[qh][0][i] = 0.f; acc_o[qh][1][i] = 0.f; }

    // ---- prologue: stage tile 0 into buf 0, drain, barrier
    async_ld16(gK0, &lK[c0 * 8]);
    async_ld16(gK1, &lK[c1 * 8]);
    async_ld16(gV0, &lV[c0 * 8]);
    async_ld16(gV1, &lV[c1 * 8]);
    asm volatile("s_waitcnt vmcnt(0)\n\ts_barrier" ::: "memory");

    int cur = 0;
    const int NT = SEQ / 64;       // 32
    for (int t = 0; t < NT; ++t) {
        // ---- issue next-tile DMA first; latency hides under this tile's math
        if (t + 1 < NT) {
            const int kv0 = (t + 1) * 64;
            const int nb = (cur ^ 1) * 4096;
            async_ld16(gK0 + (size_t)kv0 * D_MODEL, &lK[nb + c0 * 8]);
            async_ld16(gK1 + (size_t)kv0 * D_MODEL, &lK[nb + c1 * 8]);
            async_ld16(gV0 + kv0, &lV[nb + c0 * 8]);
            async_ld16(gV1 + kv0, &lV[nb + c1 * 8]);
        }
        const bf16_t* lKc = lK + cur * 4096;
        const bf16_t* lVc = lV + cur * 4096;

        // ---- S^T: D[m = kv-local(32)][n = q(32)], shared kf across both qh
        bf16x8 kf[4];
#pragma unroll
        for (int c = 0; c < 4; ++c) kf[c] = *(const bf16x8*)&lKc[koff[c]];

        f32x16 st[2];
#pragma unroll
        for (int qh = 0; qh < 2; ++qh)
#pragma unroll
            for (int i = 0; i < 16; ++i) st[qh][i] = 0.f;
        __builtin_amdgcn_s_setprio(1);
#pragma unroll
        for (int qh = 0; qh < 2; ++qh)
#pragma unroll
            for (int c = 0; c < 4; ++c)
                st[qh] = __builtin_amdgcn_mfma_f32_32x32x16_bf16(
                    kf[c], qf[qh][c], st[qh], 0, 0, 0);
        __builtin_amdgcn_s_setprio(0);

        // ---- exp2 + pack + f32 rowsum (tree adds; lane's st col is q = l31)
        bf16x4 pk[2][4];
#pragma unroll
        for (int qh = 0; qh < 2; ++qh)
#pragma unroll
            for (int g = 0; g < 4; ++g) {
                const float e0 = __builtin_amdgcn_exp2f(st[qh][g * 4 + 0]);
                const float e1 = __builtin_amdgcn_exp2f(st[qh][g * 4 + 1]);
                const float e2 = __builtin_amdgcn_exp2f(st[qh][g * 4 + 2]);
                const float e3 = __builtin_amdgcn_exp2f(st[qh][g * 4 + 3]);
                pk[qh][g][0] = (bf16_t)e0; pk[qh][g][1] = (bf16_t)e1;
                pk[qh][g][2] = (bf16_t)e2; pk[qh][g][3] = (bf16_t)e3;
                rsumf[qh] += (e0 + e1) + (e2 + e3);
            }

        // ---- assemble PV A-frags via permlane32_swap:
        // pf[qh][ck] = A[m = q = l31][k = kv-local 16ck + 8h + j]
        bf16x8 pf[2][2];
#pragma unroll
        for (int qh = 0; qh < 2; ++qh)
#pragma unroll
            for (int ck = 0; ck < 2; ++ck) {
                union { bf16x4 v; uint32_t d[2]; } ua, ub;
                ua.v = pk[qh][2 * ck];
                ub.v = pk[qh][2 * ck + 1];
                uint32_t a0 = ua.d[0], b0 = ub.d[0];
                uint32_t a1 = ua.d[1], b1 = ub.d[1];
                plswap(a0, b0);
                plswap(a1, b1);
                union { bf16x8 v; uint32_t d[4]; } up;
                up.d[0] = a0; up.d[1] = a1; up.d[2] = b0; up.d[3] = b1;
                pf[qh][ck] = up.v;
            }

        // ---- PV (row-sum MFMAs removed: 20 -> 16 MFMA per wave-iter)
        __builtin_amdgcn_s_setprio(1);
#pragma unroll
        for (int a = 0; a < 2; ++a)
#pragma unroll
            for (int ck = 0; ck < 2; ++ck) {
                bf16x8 vf = *(const bf16x8*)&lVc[voff[a][ck]];
#pragma unroll
                for (int qh = 0; qh < 2; ++qh)
                    acc_o[qh][a] = __builtin_amdgcn_mfma_f32_32x32x16_bf16(
                        pf[qh][ck], vf, acc_o[qh][a], 0, 0, 0);
            }
        __builtin_amdgcn_s_setprio(0);

        // ---- own DMA + LDS ops drained, then block rendezvous (one asm so
        // nothing is scheduled between the waits and the barrier).
        asm volatile("s_waitcnt vmcnt(0) lgkmcnt(0)\n\ts_barrier" ::: "memory");
        cur ^= 1;
    }

    // ---- epilogue ------------------------------------------------------
    // 1) h-combine: partner lane (l^32) holds the other 16 kv slots of q=l31.
#pragma unroll
    for (int qh = 0; qh < 2; ++qh)
        rsumf[qh] += __shfl_xor(rsumf[qh], 32);

    // 2) wk-combine through LDS blobs (loop's final barrier: all reads done).
    union F16 { f32x16 v; f32x4 q[4]; };
    float* blob = (float*)arena + ((size_t)(wq * 64 + lane)) * 68;  // 272B stride
    float* sbuf = (float*)(arena + 34816);                          // 128 floats

    if (wk) {
#pragma unroll
        for (int qh = 0; qh < 2; ++qh)
#pragma unroll
            for (int a = 0; a < 2; ++a) {
                F16 u; u.v = acc_o[qh][a];
#pragma unroll
                for (int i = 0; i < 4; ++i)
                    *(f32x4*)&blob[(qh * 8 + a * 4 + i) * 4] = u.q[i];
            }
        blob[64] = rsumf[0];
        blob[65] = rsumf[1];
    }
    __syncthreads();
    if (!wk) {
#pragma unroll
        for (int qh = 0; qh < 2; ++qh)
#pragma unroll
            for (int a = 0; a < 2; ++a) {
                F16 u; u.v = acc_o[qh][a];
#pragma unroll
                for (int i = 0; i < 4; ++i)
                    u.q[i] += *(const f32x4*)&blob[(qh * 8 + a * 4 + i) * 4];
                acc_o[qh][a] = u.v;
            }
        rsumf[0] += blob[64];
        rsumf[1] += blob[65];
        // 3) publish full rowsum keyed by tile-local q (h=1 lanes duplicate)
        if (h == 0) {
            sbuf[wq * 64 + l31]      = rsumf[0];
            sbuf[wq * 64 + 32 + l31] = rsumf[1];
        }
    }
    __syncthreads();   // all threads reach (wk=1 idle but participating)
    if (!wk) {
        // 4) O / rowsum; C-layout row = r + 8g + 4h, col = l31. sbuf read is
        // same-address across the 32 lanes -> LDS broadcast (free).
#pragma unroll
        for (int qh = 0; qh < 2; ++qh)
#pragma unroll
            for (int g = 0; g < 4; ++g)
#pragma unroll
                for (int r = 0; r < 4; ++r) {
                    const int rl = r + 8 * g + 4 * h;       // row within qh strip
                    const float inv = 1.0f / sbuf[wq * 64 + qh * 32 + rl];
                    const int row = b_ * SEQ + q0 + wq * 64 + qh * 32 + rl;
                    const size_t rb = (size_t)row * D_MODEL + hh * DHEAD + l31;
                    Ob[rb]      = (bf16_t)(acc_o[qh][0][g * 4 + r] * inv);
                    Ob[rb + 32] = (bf16_t)(acc_o[qh][1][g * 4 + r] * inv);
                }
    }
}

// ---------------------------------------------------------------------------
extern "C" void kernel_launch(void* const* d_in, const int* in_sizes, int n_in,
                              void* d_out, int out_size, void* d_ws, size_t ws_size,
                              hipStream_t stream)
{
    const float* x  = (const float*)d_in[0];
    const float* Wq = (const float*)d_in[1];
    const float* Wk = (const float*)d_in[2];
    const float* Wv = (const float*)d_in[3];
    const float* Wo = (const float*)d_in[4];
    float* out = (float*)d_out;

    const size_t wmat = (size_t)D_MODEL * D_MODEL;  // 1M elements
    const size_t mat  = (size_t)NROWS * D_MODEL;    // 4M elements
    bf16_t* Wqb = (bf16_t*)d_ws;
    bf16_t* Wkb = Wqb + wmat;
    bf16_t* Wvb = Wkb + wmat;
    bf16_t* Wob = Wvb + wmat;
    bf16_t* Xb  = Wob + wmat;
    bf16_t* Qb  = Xb + mat;
    bf16_t* Kb  = Qb + mat;
    bf16_t* Vt  = Kb + mat;                          // [bh][dh][s]
    bf16_t* Ab  = Qb;                                // alias (see k_attn)

    dim3 blk(256);
    k_cvt<<<dim3(4096), blk, 0, stream>>>(Wq, Wk, Wv, Wo, x, Wqb, Wkb, Wvb, Wob, Xb);
    k_gemm_qkv<<<dim3(32, 24), blk, 0, stream>>>(Xb, Wqb, Wkb, Wvb, Qb, Kb, Vt);
    k_attn<<<dim3(32, 16), blk, 0, stream>>>(Qb, Kb, Vt, Ab);
    k_gemm_out<<<dim3(32, 8), blk, 0, stream>>>(Ab, Wob, out);
}

// Round 11
// 172.044 us; speedup vs baseline: 1.0777x; 1.0359x over previous
//
#include <hip/hip_runtime.h>
#include <stdint.h>

typedef __bf16 bf16_t;
typedef __bf16 bf16x4 __attribute__((ext_vector_type(4)));
typedef __bf16 bf16x8 __attribute__((ext_vector_type(8)));
typedef float  f32x4  __attribute__((ext_vector_type(4)));
typedef float  f32x16 __attribute__((ext_vector_type(16)));

#define D_MODEL 1024
#define SEQ     2048
#define BATCH   2
#define NHEAD   16
#define DHEAD   64
#define NROWS   (BATCH*SEQ)   // 4096
#define LDT     72            // GEMM V-transpose buffer stride (16B-aligned)

// log2(e): folded into Q scale so attn uses v_exp_f32 (exp2) directly.
#define QSCALE  (0.125f * 1.4426950408889634f)

// async 16B global->LDS DMA (m97). LDS dest must be wave-uniform base + lane*16.
__device__ __forceinline__ void async_ld16(const bf16_t* g, bf16_t* l) {
    __builtin_amdgcn_global_load_lds(
        (const __attribute__((address_space(1))) uint32_t*)(uintptr_t)g,
        (__attribute__((address_space(3))) uint32_t*)(uintptr_t)l,
        16, 0, 0);
}

__device__ __forceinline__ bf16x8 cvt8(f32x4 lo, f32x4 hi) {
    bf16x8 o;
#pragma unroll
    for (int i = 0; i < 4; ++i) { o[i] = (bf16_t)lo[i]; o[4 + i] = (bf16_t)hi[i]; }
    return o;
}

// v_permlane32_swap_b32 a, b:  a'[l<32]=a[l], a'[l>=32]=b[l-32];
//                              b'[l<32]=a[l+32], b'[l>=32]=b[l]
__device__ __forceinline__ void plswap(uint32_t& a, uint32_t& b) {
    asm("v_permlane32_swap_b32 %0, %1" : "+v"(a), "+v"(b));
}

// ---------------------------------------------------------------------------
// f32 -> bf16 pre-convert of Wq,Wk,Wv,Wo (512 blocks each) + x (2048 blocks).
// ---------------------------------------------------------------------------
__global__ void __launch_bounds__(256)
k_cvt(const float* __restrict__ w0, const float* __restrict__ w1,
      const float* __restrict__ w2, const float* __restrict__ w3,
      const float* __restrict__ x,
      bf16_t* __restrict__ o0, bf16_t* __restrict__ o1,
      bf16_t* __restrict__ o2, bf16_t* __restrict__ o3,
      bf16_t* __restrict__ ox)
{
    const int blk = blockIdx.x;
    const float* s; bf16_t* d; int bi;
    if (blk < 2048) { s = x; d = ox; bi = blk; }
    else {
        const int t = blk - 2048, sel = t >> 9; bi = t & 511;
        s = (sel == 0) ? w0 : (sel == 1) ? w1 : (sel == 2) ? w2 : w3;
        d = (sel == 0) ? o0 : (sel == 1) ? o1 : (sel == 2) ? o2 : o3;
    }
    const size_t i = ((size_t)bi * 256 + threadIdx.x) * 8;
    *(bf16x8*)(d + i) = cvt8(*(const f32x4*)(s + i), *(const f32x4*)(s + i + 4));
}

// ---------------------------------------------------------------------------
// MT x 128 GEMM tile: Y = X @ W^T * oscale. A and B bf16. MT in {64,128}.
// Staging: global_load_lds width=16, 32-elem LDS rows, XOR-4 chunk swizzle.
// DBUF=false: serial loop (sync -> STAGE -> sync -> compute).
// DBUF=true : 2-phase stage-ahead via __syncthreads() only (no inline asm).
//   Invariant: each __syncthreads() drains every wave's DMA (vmcnt) and
//   ds_reads (lgkmcnt) then barriers -> next iter reads buf^1 fully staged
//   and overwrites buf with no pending readers. Measured null at 3 blocks/CU
//   (qkv, r9 — implicit inter-block overlap already hides the drain) but the
//   mechanism matters at 1 block/CU (out) where NO other work exists to hide
//   the DMA round-trip.
// OUT_MODE: 0 = bf16 row-major; 1 = bf16 V^T [bh][dh][s] (MT=128 only);
//           2 = f32 row-major.
// ---------------------------------------------------------------------------
template <int OUT_MODE, int MT, bool DBUF>
__device__ __forceinline__ void gemmT(bf16_t* __restrict__ smem,
                                      const bf16_t* __restrict__ X,
                                      const bf16_t* __restrict__ W,
                                      void* __restrict__ Yv,
                                      int m0, int n0, float oscale)
{
    constexpr int FM  = MT / 32;           // A-frags (16-row) per wave
    constexpr int BUF = (MT + 128) * 32;   // elems per LDS buffer

    const int tid  = threadIdx.x;
    const int lane = tid & 63;
    const int w    = tid >> 6;
    const int l15  = lane & 15;
    const int quad = lane >> 4;

    // B staging: 512 chunks, 2 per thread
    const int cB0 = tid, cB1 = tid + 256;
    const int rB0 = cB0 >> 2, rB1 = cB1 >> 2;
    const int kB0 = (cB0 & 3) ^ ((rB0 >> 1) & 3);
    const int kB1 = (cB1 & 3) ^ ((rB1 >> 1) & 3);
    const bf16_t* gB0 = W + (size_t)(n0 + rB0) * D_MODEL + kB0 * 8;
    const bf16_t* gB1 = W + (size_t)(n0 + rB1) * D_MODEL + kB1 * 8;

    // A staging: MT*4 chunks (MT=128: 2/thread, MT=64: 1/thread)
    const int cA0 = tid;
    const int rA0 = cA0 >> 2;
    const int kA0 = (cA0 & 3) ^ ((rA0 >> 1) & 3);
    const bf16_t* gA0 = X + (size_t)(m0 + rA0) * D_MODEL + kA0 * 8;
    const int cA1 = tid + 256;
    const int rA1 = cA1 >> 2;
    const int kA1 = (cA1 & 3) ^ ((rA1 >> 1) & 3);
    const bf16_t* gA1 = X + (size_t)(m0 + rA1) * D_MODEL + kA1 * 8;

    int am[FM], bn[4];
    const int mw = (w >> 1) * (MT / 2), nw = (w & 1) * 64;
#pragma unroll
    for (int i = 0; i < FM; ++i) {
        const int ra = mw + i * 16 + l15;
        am[i] = ra * 32 + (quad ^ ((ra >> 1) & 3)) * 8;
    }
#pragma unroll
    for (int i = 0; i < 4; ++i) {
        const int rb = nw + i * 16 + l15;
        bn[i] = rb * 32 + (quad ^ ((rb >> 1) & 3)) * 8;
    }

    f32x4 acc[FM][4];
#pragma unroll
    for (int i = 0; i < FM; ++i)
#pragma unroll
        for (int j = 0; j < 4; ++j) acc[i][j] = f32x4{0.f, 0.f, 0.f, 0.f};

    auto STAGE = [&](int k0, int b) {
        bf16_t* lA = smem + b * BUF;
        bf16_t* lB = lA + MT * 32;
        async_ld16(gA0 + k0, &lA[cA0 * 8]);
        if constexpr (MT == 128) async_ld16(gA1 + k0, &lA[cA1 * 8]);
        async_ld16(gB0 + k0, &lB[cB0 * 8]);
        async_ld16(gB1 + k0, &lB[cB1 * 8]);
    };
    auto COMPUTE = [&](int b) {
        const bf16_t* lA = smem + b * BUF;
        const bf16_t* lB = lA + MT * 32;
        bf16x8 af[FM], bfr[4];
#pragma unroll
        for (int i = 0; i < FM; ++i) af[i] = *(const bf16x8*)&lA[am[i]];
#pragma unroll
        for (int i = 0; i < 4; ++i) bfr[i] = *(const bf16x8*)&lB[bn[i]];
#pragma unroll
        for (int mi = 0; mi < FM; ++mi)
#pragma unroll
            for (int ni = 0; ni < 4; ++ni)
                acc[mi][ni] = __builtin_amdgcn_mfma_f32_16x16x32_bf16(
                    af[mi], bfr[ni], acc[mi][ni], 0, 0, 0);
    };

    if constexpr (DBUF) {
        STAGE(0, 0);
        __syncthreads();
        int buf = 0;
        for (int k0 = 0; k0 < D_MODEL; k0 += 32) {
            if (k0 + 32 < D_MODEL) STAGE(k0 + 32, buf ^ 1);
            COMPUTE(buf);
            __syncthreads();
            buf ^= 1;
        }
    } else {
        for (int k0 = 0; k0 < D_MODEL; k0 += 32) {
            __syncthreads();
            STAGE(k0, 0);
            __syncthreads();
            COMPUTE(0);
        }
    }

    if constexpr (OUT_MODE == 1) {
        bf16_t* lT = smem;                        // 128 cols x LDT (reuse)
#pragma unroll
        for (int h0 = 0; h0 < 2; ++h0) {
            __syncthreads();
            if ((w >> 1) == h0) {
#pragma unroll
                for (int mi = 0; mi < FM; ++mi)
#pragma unroll
                    for (int ni = 0; ni < 4; ++ni) {
                        bf16x4 pk;
#pragma unroll
                        for (int r = 0; r < 4; ++r)
                            pk[r] = (bf16_t)(acc[mi][ni][r] * oscale);
                        const int col = nw + ni * 16 + l15;
                        *(bf16x4*)&lT[col * LDT + mi * 16 + quad * 4] = pk;
                    }
            }
            __syncthreads();
            const int col = tid & 127;
            const int seg = tid >> 7;
            const int brow = m0 + h0 * 64;
            const int b = brow >> 11, sb = brow & 2047;
            const int cg = n0 + col;              // h*64+dh
            bf16_t* dst = (bf16_t*)Yv +
                ((size_t)((b << 4) | (cg >> 6)) * 64 + (cg & 63)) * SEQ + sb;
#pragma unroll
            for (int u = 0; u < 4; ++u)
                *(bf16x8*)(dst + seg * 32 + u * 8) =
                    *(const bf16x8*)&lT[col * LDT + seg * 32 + u * 8];
        }
    } else {
        // C/D layout col = lane&15, row = quad*4 + reg (m89-verified)
#pragma unroll
        for (int mi = 0; mi < FM; ++mi)
#pragma unroll
            for (int ni = 0; ni < 4; ++ni)
#pragma unroll
                for (int r = 0; r < 4; ++r) {
                    const int row = m0 + mw + mi * 16 + quad * 4 + r;
                    const int col = n0 + nw + ni * 16 + l15;
                    const float vv = acc[mi][ni][r] * oscale;
                    if constexpr (OUT_MODE == 0)
                        ((bf16_t*)Yv)[(size_t)row * D_MODEL + col] = (bf16_t)vv;
                    else
                        ((float*)Yv)[(size_t)row * D_MODEL + col] = vv;
                }
    }
}

// 768 blocks = 3/CU, plain mapping, DBUF (r9/r10 measured config).
__global__ void __launch_bounds__(256, 3)
k_gemm_qkv(const bf16_t* __restrict__ X,
           const bf16_t* __restrict__ Wq, const bf16_t* __restrict__ Wk,
           const bf16_t* __restrict__ Wv,
           bf16_t* __restrict__ Qb, bf16_t* __restrict__ Kb, bf16_t* __restrict__ Vt)
{
    __shared__ __align__(16) bf16_t smem[16384];       // 32 KiB: 2 x (128+128)x32
    const int sel = blockIdx.y >> 3;           // 0=Q 1=K 2=V
    const int n0  = (blockIdx.y & 7) * 128;
    const int m0  = blockIdx.x * 128;
    if (sel == 0)      gemmT<0,128,true>(smem, X, Wq, Qb, m0, n0, QSCALE);
    else if (sel == 1) gemmT<0,128,true>(smem, X, Wk, Kb, m0, n0, 1.0f);
    else               gemmT<1,128,true>(smem, X, Wv, Vt, m0, n0, 1.0f);
}

// Round-11: 256 blocks = 1 block/CU = 1 wave/SIMD -> the serial stage loop
// had NOTHING to hide the per-iter DMA round-trip under (no 2nd block, no
// 2nd wave). DBUF stage-ahead is the only available latency hiding here.
__global__ void __launch_bounds__(256, 3)
k_gemm_out(const bf16_t* __restrict__ X, const bf16_t* __restrict__ W,
           float* __restrict__ Y)
{
    __shared__ __align__(16) bf16_t smem[16384];       // 32 KiB: 2 x (128+128)x32
    gemmT<2,128,true>(smem, X, W, Y, blockIdx.x * 128, blockIdx.y * 128, 1.0f);
}

// ---------------------------------------------------------------------------
// Attention — byte-exact r2/r9 kernel (best measured: 48.4-48.5 us, passed
// 4x). Q-tile 128, 4 waves 2x2: wq = 64-row q-strip, wk = 32-row kv-half.
// Per wave-iter: 4 K + 4 V ds_read_b128 (each serving 2 qh), 20 MFMA, 32
// exp2. Partner h-exchange via v_permlane32_swap_b32. Row-sum via
// ones-column MFMA (acc_s layout == acc_o; r10's VALU-rowsum variant was
// consistently ~0.5us slower — VALU is the busier pipe). Double-buffered
// K/V; stage t+1 before compute of t; ONE fused vmcnt/lgkmcnt + barrier per
// tile. Epilogue combines wk pairs once through the reused LDS arena.
// Ob may alias Qb (Q read to regs up-front; block-disjoint slices).
// ---------------------------------------------------------------------------
__global__ void __launch_bounds__(256, 2)
k_attn(const bf16_t* __restrict__ Qb, const bf16_t* __restrict__ Kb,
       const bf16_t* __restrict__ Vt, bf16_t* __restrict__ Ob)
{
    // arena: main loop lK[2][4096]+lV[2][4096] bf16 (32 KiB);
    // epilogue reuses it as 2 x 64 blobs of 96 floats (stride 100 -> 50 KiB).
    __shared__ __align__(16) char arena[51200];
    bf16_t* lK = (bf16_t*)arena;               // [2][64*64] swizzled chunks
    bf16_t* lV = (bf16_t*)(arena + 16384);     // [2][64*64] swizzled chunks

    const int tid  = threadIdx.x;
    const int lane = tid & 63;
    const int w    = tid >> 6;
    const int wq   = w >> 1;      // q-strip (64 rows)
    const int wk   = w & 1;       // kv-half (32 rows)
    const int l31  = lane & 31;
    const int h    = lane >> 5;

    const int bh = blockIdx.x;    // 0..31
    const int b_ = bh >> 4, hh = bh & 15;
    const int q0 = blockIdx.y * 128;

    const size_t base = (size_t)b_ * SEQ * D_MODEL + (size_t)hh * DHEAD;
    const bf16_t* Qp = Qb + base;
    const bf16_t* Kp = Kb + base;
    const bf16_t* Vp = Vt + (size_t)bh * DHEAD * SEQ;   // [dh][s]

    // Q B-frags in regs: B[n = q = l31][k = dh-local h*8+j], chunk c = dh/16
    bf16x8 qf[2][4];
#pragma unroll
    for (int qh = 0; qh < 2; ++qh) {
        const int qrow = q0 + wq * 64 + qh * 32 + l31;
#pragma unroll
        for (int c = 0; c < 4; ++c)
            qf[qh][c] = *(const bf16x8*)&Qp[(size_t)qrow * D_MODEL + c * 16 + h * 8];
    }

    // staging: 512 chunks per tile, 2 per thread; chunk c -> row c>>3, slot
    // c&7, global chunk g = (c&7) ^ (row&7). Note (r0+32)&7 == r0&7.
    const int c0 = tid, c1 = tid + 256;
    const int r0 = c0 >> 3, g0 = (c0 & 7) ^ (r0 & 7);
    const int r1 = r0 + 32;
    const bf16_t* gK0 = Kp + (size_t)r0 * D_MODEL + g0 * 8;
    const bf16_t* gK1 = Kp + (size_t)r1 * D_MODEL + g0 * 8;
    const bf16_t* gV0 = Vp + (size_t)r0 * SEQ + g0 * 8;
    const bf16_t* gV1 = Vp + (size_t)r1 * SEQ + g0 * 8;

    // fragment read offsets (row-dependent XOR slot)
    int koff[4], voff[2][2];
#pragma unroll
    for (int c = 0; c < 4; ++c) {
        const int row = wk * 32 + l31;               // kv row (wave's half)
        koff[c] = row * 64 + (((2 * c + h) ^ (row & 7)) * 8);
    }
#pragma unroll
    for (int a = 0; a < 2; ++a)
#pragma unroll
        for (int ck = 0; ck < 2; ++ck) {
            const int row = a * 32 + l31;            // dh row
            const int ch  = 4 * wk + 2 * ck + h;     // kv chunk within row
            voff[a][ck] = row * 64 + ((ch ^ (row & 7)) * 8);
        }

    bf16x8 onef;
#pragma unroll
    for (int i = 0; i < 8; ++i) onef[i] = (bf16_t)1.0f;

    f32x16 acc_o[2][2];            // [qh][a]  D[m=q][n=dh]
    f32x16 acc_s[2];               // [qh]     rowsum (ones-column PV)
#pragma unroll
    for (int qh = 0; qh < 2; ++qh) {
#pragma unroll
        for (int i = 0; i < 16; ++i) {
            acc_o[qh][0][i] = 0.f; acc_o[qh][1][i] = 0.f; acc_s[qh][i] = 0.f;
        }
    }

    // ---- prologue: stage tile 0 into buf 0, drain, barrier
    async_ld16(gK0, &lK[c0 * 8]);
    async_ld16(gK1, &lK[c1 * 8]);
    async_ld16(gV0, &lV[c0 * 8]);
    async_ld16(gV1, &lV[c1 * 8]);
    asm volatile("s_waitcnt vmcnt(0)\n\ts_barrier" ::: "memory");

    int cur = 0;
    const int NT = SEQ / 64;       // 32
    for (int t = 0; t < NT; ++t) {
        // ---- issue next-tile DMA first; latency hides under this tile's math
        if (t + 1 < NT) {
            const int kv0 = (t + 1) * 64;
            const int nb = (cur ^ 1) * 4096;
            async_ld16(gK0 + (size_t)kv0 * D_MODEL, &lK[nb + c0 * 8]);
            async_ld16(gK1 + (size_t)kv0 * D_MODEL, &lK[nb + c1 * 8]);
            async_ld16(gV0 + kv0, &lV[nb + c0 * 8]);
            async_ld16(gV1 + kv0, &lV[nb + c1 * 8]);
        }
        const bf16_t* lKc = lK + cur * 4096;
        const bf16_t* lVc = lV + cur * 4096;

        // ---- S^T: D[m = kv-local(32)][n = q(32)], shared kf across both qh
        bf16x8 kf[4];
#pragma unroll
        for (int c = 0; c < 4; ++c) kf[c] = *(const bf16x8*)&lKc[koff[c]];

        f32x16 st[2];
#pragma unroll
        for (int qh = 0; qh < 2; ++qh)
#pragma unroll
            for (int i = 0; i < 16; ++i) st[qh][i] = 0.f;
        __builtin_amdgcn_s_setprio(1);
#pragma unroll
        for (int qh = 0; qh < 2; ++qh)
#pragma unroll
            for (int c = 0; c < 4; ++c)
                st[qh] = __builtin_amdgcn_mfma_f32_32x32x16_bf16(
                    kf[c], qf[qh][c], st[qh], 0, 0, 0);
        __builtin_amdgcn_s_setprio(0);

        // ---- exp2 + pack: pk[qh][g][r] = P[kv-local = 8g+4h+r][q = l31]
        bf16x4 pk[2][4];
#pragma unroll
        for (int qh = 0; qh < 2; ++qh)
#pragma unroll
            for (int g = 0; g < 4; ++g)
#pragma unroll
                for (int r = 0; r < 4; ++r)
                    pk[qh][g][r] = (bf16_t)__builtin_amdgcn_exp2f(st[qh][g * 4 + r]);

        // ---- assemble PV A-frags via permlane32_swap:
        // pf[qh][ck] = A[m = q = l31][k = kv-local 16ck + 8h + j]
        bf16x8 pf[2][2];
#pragma unroll
        for (int qh = 0; qh < 2; ++qh)
#pragma unroll
            for (int ck = 0; ck < 2; ++ck) {
                union { bf16x4 v; uint32_t d[2]; } ua, ub;
                ua.v = pk[qh][2 * ck];
                ub.v = pk[qh][2 * ck + 1];
                uint32_t a0 = ua.d[0], b0 = ub.d[0];
                uint32_t a1 = ua.d[1], b1 = ub.d[1];
                plswap(a0, b0);
                plswap(a1, b1);
                union { bf16x8 v; uint32_t d[4]; } up;
                up.d[0] = a0; up.d[1] = a1; up.d[2] = b0; up.d[3] = b1;
                pf[qh][ck] = up.v;
            }

        // ---- PV + ones-column row-sum
        __builtin_amdgcn_s_setprio(1);
#pragma unroll
        for (int qh = 0; qh < 2; ++qh)
#pragma unroll
            for (int ck = 0; ck < 2; ++ck)
                acc_s[qh] = __builtin_amdgcn_mfma_f32_32x32x16_bf16(
                    pf[qh][ck], onef, acc_s[qh], 0, 0, 0);
#pragma unroll
        for (int a = 0; a < 2; ++a)
#pragma unroll
            for (int ck = 0; ck < 2; ++ck) {
                bf16x8 vf = *(const bf16x8*)&lVc[voff[a][ck]];
#pragma unroll
                for (int qh = 0; qh < 2; ++qh)
                    acc_o[qh][a] = __builtin_amdgcn_mfma_f32_32x32x16_bf16(
                        pf[qh][ck], vf, acc_o[qh][a], 0, 0, 0);
            }
        __builtin_amdgcn_s_setprio(0);

        // ---- own DMA + LDS ops drained, then block rendezvous (one asm so
        // nothing is scheduled between the waits and the barrier).
        asm volatile("s_waitcnt vmcnt(0) lgkmcnt(0)\n\ts_barrier" ::: "memory");
        cur ^= 1;
    }

    // ---- epilogue: combine wk pairs through LDS (arena reused; loop's final
    // barrier guarantees all tile reads are done).
    union F16 { f32x16 v; f32x4 q[4]; };
    float* blob = (float*)arena + ((size_t)(wq * 64 + lane)) * 100;  // 400B stride

    if (wk) {
#pragma unroll
        for (int qh = 0; qh < 2; ++qh) {
#pragma unroll
            for (int a = 0; a < 2; ++a) {
                F16 u; u.v = acc_o[qh][a];
#pragma unroll
                for (int i = 0; i < 4; ++i)
                    *(f32x4*)&blob[(qh * 8 + a * 4 + i) * 4] = u.q[i];
            }
            F16 s; s.v = acc_s[qh];
#pragma unroll
            for (int i = 0; i < 4; ++i)
                *(f32x4*)&blob[64 + (qh * 4 + i) * 4] = s.q[i];
        }
    }
    __syncthreads();
    if (!wk) {
#pragma unroll
        for (int qh = 0; qh < 2; ++qh) {
#pragma unroll
            for (int a = 0; a < 2; ++a) {
                F16 u; u.v = acc_o[qh][a];
#pragma unroll
                for (int i = 0; i < 4; ++i)
                    u.q[i] += *(const f32x4*)&blob[(qh * 8 + a * 4 + i) * 4];
                acc_o[qh][a] = u.v;
            }
            F16 s; s.v = acc_s[qh];
#pragma unroll
            for (int i = 0; i < 4; ++i)
                s.q[i] += *(const f32x4*)&blob[64 + (qh * 4 + i) * 4];
            acc_s[qh] = s.v;
        }

        // O / rowsum; 32x32 C-layout row = r + 8g + 4h, col = l31
#pragma unroll
        for (int qh = 0; qh < 2; ++qh)
#pragma unroll
            for (int g = 0; g < 4; ++g)
#pragma unroll
                for (int r = 0; r < 4; ++r) {
                    const float inv = 1.0f / acc_s[qh][g * 4 + r];
                    const int row = b_ * SEQ + q0 + wq * 64 + qh * 32 + (r + 8 * g + 4 * h);
                    const size_t rb = (size_t)row * D_MODEL + hh * DHEAD + l31;
                    Ob[rb]      = (bf16_t)(acc_o[qh][0][g * 4 + r] * inv);
                    Ob[rb + 32] = (bf16_t)(acc_o[qh][1][g * 4 + r] * inv);
                }
    }
}

// ---------------------------------------------------------------------------
extern "C" void kernel_launch(void* const* d_in, const int* in_sizes, int n_in,
                              void* d_out, int out_size, void* d_ws, size_t ws_size,
                              hipStream_t stream)
{
    const float* x  = (const float*)d_in[0];
    const float* Wq = (const float*)d_in[1];
    const float* Wk = (const float*)d_in[2];
    const float* Wv = (const float*)d_in[3];
    const float* Wo = (const float*)d_in[4];
    float* out = (float*)d_out;

    const size_t wmat = (size_t)D_MODEL * D_MODEL;  // 1M elements
    const size_t mat  = (size_t)NROWS * D_MODEL;    // 4M elements
    bf16_t* Wqb = (bf16_t*)d_ws;
    bf16_t* Wkb = Wqb + wmat;
    bf16_t* Wvb = Wkb + wmat;
    bf16_t* Wob = Wvb + wmat;
    bf16_t* Xb  = Wob + wmat;
    bf16_t* Qb  = Xb + mat;
    bf16_t* Kb  = Qb + mat;
    bf16_t* Vt  = Kb + mat;                          // [bh][dh][s]
    bf16_t* Ab  = Qb;                                // alias (see k_attn)

    dim3 blk(256);
    k_cvt<<<dim3(4096), blk, 0, stream>>>(Wq, Wk, Wv, Wo, x, Wqb, Wkb, Wvb, Wob, Xb);
    k_gemm_qkv<<<dim3(32, 24), blk, 0, stream>>>(Xb, Wqb, Wkb, Wvb, Qb, Kb, Vt);
    k_attn<<<dim3(32, 16), blk, 0, stream>>>(Qb, Kb, Vt, Ab);
    k_gemm_out<<<dim3(32, 8), blk, 0, stream>>>(Ab, Wob, out);
}